// Round 6
// baseline (627.830 us; speedup 1.0000x reference)
//
#include <hip/hip_runtime.h>

#define N_NODES   50000
#define N_EDGES   1600000
#define N_GRAPHS  512
#define IN_SIZE   44
#define HIDDEN    256
#define CONV_NUMS 3
#define NBK       ((N_NODES + 255) / 256)   // 196 dst-buckets of 256 nodes

typedef __attribute__((ext_vector_type(8))) short short8v;   // 8 bf16 = 16 B
typedef __attribute__((ext_vector_type(4))) float f32x4;     // MFMA C/D frag

__device__ __forceinline__ float bf2f(unsigned short u) {
    return __uint_as_float(((unsigned int)u) << 16);
}
__device__ __forceinline__ unsigned short f2bf(float f) {
    unsigned int u = __float_as_uint(f);
    unsigned int r = (u + 0x7fffu + ((u >> 16) & 1u)) >> 16;  // RNE
    return (unsigned short)r;
}

// ============================ graph build ===================================
// Pass A: bucket histogram (dst>>8) + per-graph node counts, LDS-aggregated.
__global__ __launch_bounds__(256) void k_passA(const int* __restrict__ dst,
                                               const int* __restrict__ gid,
                                               int* __restrict__ bucket_cnt,
                                               int* __restrict__ gcnt) {
    __shared__ int hb[NBK];
    __shared__ int hg[N_GRAPHS];
    int tid = threadIdx.x;
    for (int i = tid; i < NBK; i += 256) hb[i] = 0;
    for (int i = tid; i < N_GRAPHS; i += 256) hg[i] = 0;
    __syncthreads();
    int t = blockIdx.x * 256 + tid;
    int stride = gridDim.x * 256;
    for (int e = t; e < N_EDGES; e += stride) atomicAdd(&hb[dst[e] >> 8], 1);
    for (int v = t; v < N_NODES; v += stride) atomicAdd(&hg[gid[v]], 1);
    __syncthreads();
    for (int i = tid; i < NBK; i += 256) if (hb[i]) atomicAdd(&bucket_cnt[i], hb[i]);
    for (int i = tid; i < N_GRAPHS; i += 256) if (hg[i]) atomicAdd(&gcnt[i], hg[i]);
}

// scan of 196 bucket counts -> bucket_base / bucket_cursor
__global__ void k_bscan(const int* __restrict__ bucket_cnt, int* __restrict__ bucket_base,
                        int* __restrict__ bucket_cursor, int* __restrict__ row_ptr) {
    __shared__ int s[256];
    int t = threadIdx.x;
    int v = (t < NBK) ? bucket_cnt[t] : 0;
    s[t] = v;
    __syncthreads();
    for (int off = 1; off < 256; off <<= 1) {
        int a = (t >= off) ? s[t - off] : 0;
        __syncthreads();
        s[t] += a;
        __syncthreads();
    }
    if (t < NBK) {
        int base = s[t] - v;
        bucket_base[t] = base;
        bucket_cursor[t] = base;
    }
    if (t == 0) {
        bucket_base[NBK] = N_EDGES;
        row_ptr[N_NODES] = N_EDGES;
    }
}

// Pass B: LDS-sort 4096-edge chunks by bucket; payload packed into one int:
// (bucket<<24) | (local_dst<<16) | src   (src < 65536, local_dst < 256, b < 196)
#define BCH 4096
__global__ __launch_bounds__(256) void k_passB(const int* __restrict__ src,
                                               const int* __restrict__ dst,
                                               int* __restrict__ bucket_cursor,
                                               int* __restrict__ pairs) {
    __shared__ int hist[NBK];
    __shared__ int excl[NBK];
    __shared__ int cur[NBK];
    __shared__ int gbase[NBK];
    __shared__ int lp[BCH];
    __shared__ int sc[256];
    int tid = threadIdx.x;
    int e0 = blockIdx.x * BCH;
    int cnt = min(BCH, N_EDGES - e0);
    for (int i = tid; i < NBK; i += 256) hist[i] = 0;
    __syncthreads();
    for (int i = tid; i < cnt; i += 256) atomicAdd(&hist[dst[e0 + i] >> 8], 1);
    __syncthreads();
    int hv = (tid < NBK) ? hist[tid] : 0;
    sc[tid] = hv;
    __syncthreads();
    for (int off = 1; off < 256; off <<= 1) {
        int a = (tid >= off) ? sc[tid - off] : 0;
        __syncthreads();
        sc[tid] += a;
        __syncthreads();
    }
    if (tid < NBK) {
        excl[tid] = sc[tid] - hv;
        cur[tid]  = sc[tid] - hv;
    }
    __syncthreads();
    for (int i = tid; i < cnt; i += 256) {
        int d = dst[e0 + i];
        int b = d >> 8;
        int pos = atomicAdd(&cur[b], 1);
        lp[pos] = (b << 24) | ((d & 255) << 16) | src[e0 + i];
    }
    __syncthreads();
    if (tid < NBK && hist[tid] > 0)
        gbase[tid] = atomicAdd(&bucket_cursor[tid], hist[tid]);
    __syncthreads();
    for (int i = tid; i < cnt; i += 256) {
        int p = lp[i];
        int b = (p >> 24) & 0xff;
        pairs[gbase[b] + (i - excl[b])] = p;
    }
}

// Pass C: one block per bucket -> row_ptr + col (ushort; writes single-CU local)
__global__ __launch_bounds__(256) void k_passC(const int* __restrict__ pairs,
                                               const int* __restrict__ bucket_base,
                                               int* __restrict__ row_ptr,
                                               unsigned short* __restrict__ colu) {
    __shared__ int hist[256];
    __shared__ int cur[256];
    __shared__ int sc[256];
    int b = blockIdx.x;
    int tid = threadIdx.x;
    int v0 = b << 8;
    int e0 = bucket_base[b], e1 = bucket_base[b + 1];
    hist[tid] = 0;
    __syncthreads();
    for (int i = e0 + tid; i < e1; i += 256) atomicAdd(&hist[(pairs[i] >> 16) & 0xff], 1);
    __syncthreads();
    int hv = hist[tid];
    sc[tid] = hv;
    __syncthreads();
    for (int off = 1; off < 256; off <<= 1) {
        int a = (tid >= off) ? sc[tid - off] : 0;
        __syncthreads();
        sc[tid] += a;
        __syncthreads();
    }
    int base = e0 + sc[tid] - hv;
    int v = v0 + tid;
    if (v < N_NODES) row_ptr[v] = base;
    cur[tid] = base;
    __syncthreads();
    for (int i = e0 + tid; i < e1; i += 256) {
        int p = pairs[i];
        int pos = atomicAdd(&cur[(p >> 16) & 0xff], 1);
        colu[pos] = (unsigned short)(p & 0xffff);
    }
}

// ===================== W_lin repack for MFMA B-fragments ====================
__global__ __launch_bounds__(256) void k_pack_w(const float* __restrict__ W,
                                                unsigned short* __restrict__ Wp) {
    int i = blockIdx.x * 256 + threadIdx.x;   // 8192 total
    int kg = i >> 8, n = i & 255;
    short8v v;
#pragma unroll
    for (int j = 0; j < 8; j++) v[j] = (short)f2bf(W[(kg * 8 + j) * HIDDEN + n]);
    *(short8v*)(Wp + (size_t)(kg * 256 + n) * 8) = v;
}

// ============ initial projection, block-batched, W_proj in LDS ==============
__global__ __launch_bounds__(256) void k_proj(const float* __restrict__ X,
                                              const float* __restrict__ Wp,
                                              const float* __restrict__ bp,
                                              unsigned short* __restrict__ h) {
    __shared__ float WL[IN_SIZE * HIDDEN];
    __shared__ float bL[HIDDEN];
    __shared__ float xb[8 * IN_SIZE];
    int tid = threadIdx.x;
    for (int i = tid; i < IN_SIZE * HIDDEN; i += 256) WL[i] = Wp[i];
    if (tid < HIDDEN) bL[tid] = bp[tid];
    __syncthreads();
    int c = tid;
    int r0blk = blockIdx.x * 256;
    for (int batch = 0; batch < 32; batch++) {
        int r0 = r0blk + batch * 8;
        for (int i = tid; i < 8 * IN_SIZE; i += 256) {
            int g = r0 * IN_SIZE + i;
            xb[i] = (g < N_NODES * IN_SIZE) ? X[g] : 0.f;
        }
        __syncthreads();
        float acc[8];
#pragma unroll
        for (int j = 0; j < 8; j++) acc[j] = bL[c];
        for (int k = 0; k < IN_SIZE; k++) {
            float wk = WL[k * HIDDEN + c];
#pragma unroll
            for (int j = 0; j < 8; j++) acc[j] += xb[j * IN_SIZE + k] * wk;
        }
#pragma unroll
        for (int j = 0; j < 8; j++) {
            int row = r0 + j;
            if (row < N_NODES) h[(size_t)row * HIDDEN + c] = f2bf(acc[j]);
        }
        __syncthreads();
    }
}

// ====== fused layer: gather -> LDS -> MFMA -> coalesced store + readout =====
// 512 thr = 8 waves; tile 64 rows x 256 cols; LDS stride 264 shorts (33.8 KB)
// -> 4 blocks/CU = 32 waves/CU. R4's proven gather form (8 B ushort4 loads).
#define TLS 264
__global__ __launch_bounds__(512, 8) void k_layer(const unsigned short* __restrict__ h,
                                                  const int* __restrict__ row_ptr,
                                                  const unsigned short* __restrict__ colu,
                                                  const unsigned short* __restrict__ Wpack,
                                                  const float* __restrict__ bias,
                                                  const int* __restrict__ gid,
                                                  unsigned short* __restrict__ hout,
                                                  float* __restrict__ GsumL) {
    __shared__ unsigned short tl[64 * TLS];   // 33792 B
    __shared__ int gl[64];
    int tid = threadIdx.x;
    int w = tid >> 6, lane = tid & 63, quad = lane >> 4, l16 = lane & 15;
    int m0 = blockIdx.x * 64;

    // ---- phase 1: gather + mean into LDS tile (wave w -> rows w*8..w*8+8) ----
    const ushort4* hv = (const ushort4*)h;
    for (int rr = 0; rr < 8; rr++) {
        int r = w * 8 + rr;
        int v = m0 + r;
        float a0 = 0.f, a1 = 0.f, a2 = 0.f, a3 = 0.f;
        if (v < N_NODES) {
            int s = row_ptr[v], e = row_ptr[v + 1];
            int i = s;
            for (; i + 4 <= e; i += 4) {
                int u0 = colu[i], u1 = colu[i + 1], u2 = colu[i + 2], u3 = colu[i + 3];
                ushort4 p = hv[(size_t)u0 * 64 + lane];
                ushort4 q = hv[(size_t)u1 * 64 + lane];
                ushort4 x = hv[(size_t)u2 * 64 + lane];
                ushort4 y = hv[(size_t)u3 * 64 + lane];
                a0 += bf2f(p.x) + bf2f(q.x) + bf2f(x.x) + bf2f(y.x);
                a1 += bf2f(p.y) + bf2f(q.y) + bf2f(x.y) + bf2f(y.y);
                a2 += bf2f(p.z) + bf2f(q.z) + bf2f(x.z) + bf2f(y.z);
                a3 += bf2f(p.w) + bf2f(q.w) + bf2f(x.w) + bf2f(y.w);
            }
            for (; i < e; i++) {
                ushort4 p = hv[(size_t)colu[i] * 64 + lane];
                a0 += bf2f(p.x); a1 += bf2f(p.y); a2 += bf2f(p.z); a3 += bf2f(p.w);
            }
            float inv = (e > s) ? 1.0f / (float)(e - s) : 0.0f;
            ushort4 hs = hv[(size_t)v * 64 + lane];
            a0 = bf2f(hs.x) + inv * a0;
            a1 = bf2f(hs.y) + inv * a1;
            a2 = bf2f(hs.z) + inv * a2;
            a3 = bf2f(hs.w) + inv * a3;
        }
        ushort4 o;
        o.x = f2bf(a0); o.y = f2bf(a1); o.z = f2bf(a2); o.w = f2bf(a3);
        *(ushort4*)(tl + r * TLS + lane * 4) = o;
    }
    if (tid < 64) gl[tid] = (m0 + tid < N_NODES) ? gid[m0 + tid] : -1;
    __syncthreads();

    // ---- phase 2: MFMA, wave w -> cols [w*32, w*32+32) ----
    int n0 = w * 32;
    f32x4 acc[4][2];
#pragma unroll
    for (int mt = 0; mt < 4; mt++) {
        acc[mt][0] = (f32x4){0.f, 0.f, 0.f, 0.f};
        acc[mt][1] = (f32x4){0.f, 0.f, 0.f, 0.f};
    }
#pragma unroll
    for (int ks = 0; ks < 8; ks++) {
        int kg = ks * 4 + quad;
        short8v bfr0 = *(const short8v*)(Wpack + (size_t)(kg * 256 + n0 + l16) * 8);
        short8v bfr1 = *(const short8v*)(Wpack + (size_t)(kg * 256 + n0 + 16 + l16) * 8);
#pragma unroll
        for (int mt = 0; mt < 4; mt++) {
            short8v afr = *(const short8v*)(tl + (mt * 16 + l16) * TLS + ks * 32 + quad * 8);
            acc[mt][0] = __builtin_amdgcn_mfma_f32_16x16x32_bf16(afr, bfr0, acc[mt][0], 0, 0, 0);
            acc[mt][1] = __builtin_amdgcn_mfma_f32_16x16x32_bf16(afr, bfr1, acc[mt][1], 0, 0, 0);
        }
    }
    __syncthreads();  // A-frag reads complete before tile overwrite

    // ---- phase 3: epilogue -> bf16 back into LDS ----
#pragma unroll
    for (int nt = 0; nt < 2; nt++) {
        int colg = n0 + nt * 16 + l16;
        float bb = bias[colg];
#pragma unroll
        for (int mt = 0; mt < 4; mt++)
#pragma unroll
            for (int r = 0; r < 4; r++)
                tl[(mt * 16 + quad * 4 + r) * TLS + colg] = f2bf(acc[mt][nt][r] + bb);
    }
    __syncthreads();

    // ---- phase 4a: coalesced global store ----
    for (int i = tid; i < 64 * 64; i += 512) {
        int r = i >> 6, c4 = i & 63;
        int v = m0 + r;
        if (v < N_NODES)
            ((ushort4*)hout)[(size_t)v * 64 + c4] = *(ushort4*)(tl + r * TLS + c4 * 4);
    }
    // ---- phase 4b: fused readout; half 0 -> rows 0..31, half 1 -> 32..63 ----
    {
        int c = tid & 255;
        int r0 = (tid >> 8) * 32;
        float a2 = 0.f;
        int curg = gl[r0];
        for (int r = r0; r < r0 + 32; r++) {
            int g = gl[r];
            if (g < 0) break;
            if (g != curg) {
                atomicAdd(&GsumL[curg * HIDDEN + c], a2);
                a2 = 0.f;
                curg = g;
            }
            a2 += bf2f(tl[r * TLS + c]);
        }
        if (curg >= 0) atomicAdd(&GsumL[curg * HIDDEN + c], a2);
    }
}

// ================= out[g] = (concat gmean) @ W_out + b_out ==================
__global__ __launch_bounds__(256) void k_out(const float* __restrict__ Gsum,
                                             const int* __restrict__ gcnt,
                                             const float* __restrict__ Wout,
                                             const float* __restrict__ bout,
                                             float* __restrict__ out) {
    int g = blockIdx.x;
    int c = threadIdx.x;
    __shared__ float gm[HIDDEN * CONV_NUMS];
    float invc = 1.0f / fmaxf((float)gcnt[g], 1.0f);
    for (int i = c; i < HIDDEN * CONV_NUMS; i += 256) {
        int l = i >> 8;
        int k = i & 255;
        gm[i] = Gsum[(size_t)l * N_GRAPHS * HIDDEN + g * HIDDEN + k] * invc;
    }
    __syncthreads();
    float acc = bout[c];
    const float4* gm4 = (const float4*)gm;
    for (int k0 = 0; k0 < HIDDEN * CONV_NUMS; k0 += 4) {
        float4 gv = gm4[k0 >> 2];
        acc += gv.x * Wout[(k0 + 0) * HIDDEN + c];
        acc += gv.y * Wout[(k0 + 1) * HIDDEN + c];
        acc += gv.z * Wout[(k0 + 2) * HIDDEN + c];
        acc += gv.w * Wout[(k0 + 3) * HIDDEN + c];
    }
    out[g * HIDDEN + c] = acc;
}

extern "C" void kernel_launch(void* const* d_in, const int* in_sizes, int n_in,
                              void* d_out, int out_size, void* d_ws, size_t ws_size,
                              hipStream_t stream) {
    const float* X    = (const float*)d_in[0];
    const int*   src  = (const int*)d_in[1];
    const int*   dst  = (const int*)d_in[2];
    const int*   gid  = (const int*)d_in[3];
    const float* Wp   = (const float*)d_in[4];
    const float* bp   = (const float*)d_in[5];
    const float* Wl   = (const float*)d_in[6];
    const float* bl   = (const float*)d_in[7];
    const float* Wout = (const float*)d_in[8];
    const float* bout = (const float*)d_in[9];
    float* out = (float*)d_out;

    char* ws = (char*)d_ws;
    size_t off = 0;
    auto alloc = [&](size_t bytes) {
        char* p = ws + off;
        off += (bytes + 255) & ~size_t(255);
        return p;
    };
    unsigned short* h     = (unsigned short*)alloc(sizeof(short) * N_NODES * HIDDEN);
    unsigned short* t     = (unsigned short*)alloc(sizeof(short) * N_NODES * HIDDEN);
    unsigned short* Wpack = (unsigned short*)alloc(sizeof(short) * HIDDEN * HIDDEN);
    int*   pairs   = (int*)alloc(sizeof(int) * N_EDGES);
    unsigned short* colu = (unsigned short*)alloc(sizeof(short) * N_EDGES);
    int*   row_ptr = (int*)alloc(sizeof(int) * (N_NODES + 1));
    int*   bucket_base   = (int*)alloc(sizeof(int) * (NBK + 1));
    int*   bucket_cursor = (int*)alloc(sizeof(int) * NBK);
    // contiguous zero region: bucket_cnt | gcnt | Gsum  -> one memset
    char*  zero0 = ws + off;
    int*   bucket_cnt = (int*)alloc(sizeof(int) * NBK);      // padded to 1024 B
    int*   gcnt       = (int*)alloc(sizeof(int) * N_GRAPHS); // 2048 B
    float* Gsum       = (float*)alloc(sizeof(float) * CONV_NUMS * N_GRAPHS * HIDDEN);
    size_t zero_bytes = (size_t)((char*)(Gsum + CONV_NUMS * N_GRAPHS * HIDDEN) - zero0);

    hipMemsetAsync(zero0, 0, zero_bytes, stream);

    k_passA<<<512, 256, 0, stream>>>(dst, gid, bucket_cnt, gcnt);
    k_bscan<<<1, 256, 0, stream>>>(bucket_cnt, bucket_base, bucket_cursor, row_ptr);
    k_passB<<<(N_EDGES + BCH - 1) / BCH, 256, 0, stream>>>(src, dst, bucket_cursor, pairs);
    k_passC<<<NBK, 256, 0, stream>>>(pairs, bucket_base, row_ptr, colu);
    k_pack_w<<<32, 256, 0, stream>>>(Wl, Wpack);

    k_proj<<<(N_NODES + 255) / 256, 256, 0, stream>>>(X, Wp, bp, h);

    unsigned short* cur = h;
    unsigned short* nxt = t;
    for (int l = 0; l < CONV_NUMS; l++) {
        k_layer<<<(N_NODES + 63) / 64, 512, 0, stream>>>(
            cur, row_ptr, colu, Wpack, bl, gid, nxt,
            Gsum + (size_t)l * N_GRAPHS * HIDDEN);
        unsigned short* tmp = cur; cur = nxt; nxt = tmp;
    }

    k_out<<<N_GRAPHS, 256, 0, stream>>>(Gsum, gcnt, Wout, bout, out);
}

// Round 7
// 536.226 us; speedup vs baseline: 1.1708x; 1.1708x over previous
//
#include <hip/hip_runtime.h>

#define N_NODES   50000
#define N_EDGES   1600000
#define N_GRAPHS  512
#define IN_SIZE   44
#define HIDDEN    256
#define CONV_NUMS 3
#define NBK       ((N_NODES + 255) / 256)   // 196 dst-buckets of 256 nodes
#define XK        48                        // padded K for X (44 -> 48, stride)

typedef __attribute__((ext_vector_type(8))) short short8v;   // 8 bf16 = 16 B
typedef __attribute__((ext_vector_type(4))) float f32x4;     // MFMA C/D frag

__device__ __forceinline__ float bf2f(unsigned short u) {
    return __uint_as_float(((unsigned int)u) << 16);
}
__device__ __forceinline__ unsigned short f2bf(float f) {
    unsigned int u = __float_as_uint(f);
    unsigned int r = (u + 0x7fffu + ((u >> 16) & 1u)) >> 16;  // RNE
    return (unsigned short)r;
}

// ============================ graph build ===================================
__global__ __launch_bounds__(256) void k_passA(const int* __restrict__ dst,
                                               const int* __restrict__ gid,
                                               int* __restrict__ bucket_cnt,
                                               int* __restrict__ gcnt) {
    __shared__ int hb[NBK];
    __shared__ int hg[N_GRAPHS];
    int tid = threadIdx.x;
    for (int i = tid; i < NBK; i += 256) hb[i] = 0;
    for (int i = tid; i < N_GRAPHS; i += 256) hg[i] = 0;
    __syncthreads();
    int t = blockIdx.x * 256 + tid;
    int stride = gridDim.x * 256;
    for (int e = t; e < N_EDGES; e += stride) atomicAdd(&hb[dst[e] >> 8], 1);
    for (int v = t; v < N_NODES; v += stride) atomicAdd(&hg[gid[v]], 1);
    __syncthreads();
    for (int i = tid; i < NBK; i += 256) if (hb[i]) atomicAdd(&bucket_cnt[i], hb[i]);
    for (int i = tid; i < N_GRAPHS; i += 256) if (hg[i]) atomicAdd(&gcnt[i], hg[i]);
}

__global__ void k_bscan(const int* __restrict__ bucket_cnt, int* __restrict__ bucket_base,
                        int* __restrict__ bucket_cursor, int* __restrict__ row_ptr) {
    __shared__ int s[256];
    int t = threadIdx.x;
    int v = (t < NBK) ? bucket_cnt[t] : 0;
    s[t] = v;
    __syncthreads();
    for (int off = 1; off < 256; off <<= 1) {
        int a = (t >= off) ? s[t - off] : 0;
        __syncthreads();
        s[t] += a;
        __syncthreads();
    }
    if (t < NBK) {
        int base = s[t] - v;
        bucket_base[t] = base;
        bucket_cursor[t] = base;
    }
    if (t == 0) {
        bucket_base[NBK] = N_EDGES;
        row_ptr[N_NODES] = N_EDGES;
    }
}

#define BCH 4096
__global__ __launch_bounds__(256) void k_passB(const int* __restrict__ src,
                                               const int* __restrict__ dst,
                                               int* __restrict__ bucket_cursor,
                                               int* __restrict__ pairs) {
    __shared__ int hist[NBK];
    __shared__ int excl[NBK];
    __shared__ int cur[NBK];
    __shared__ int gbase[NBK];
    __shared__ int lp[BCH];
    __shared__ int sc[256];
    int tid = threadIdx.x;
    int e0 = blockIdx.x * BCH;
    int cnt = min(BCH, N_EDGES - e0);
    for (int i = tid; i < NBK; i += 256) hist[i] = 0;
    __syncthreads();
    for (int i = tid; i < cnt; i += 256) atomicAdd(&hist[dst[e0 + i] >> 8], 1);
    __syncthreads();
    int hv = (tid < NBK) ? hist[tid] : 0;
    sc[tid] = hv;
    __syncthreads();
    for (int off = 1; off < 256; off <<= 1) {
        int a = (tid >= off) ? sc[tid - off] : 0;
        __syncthreads();
        sc[tid] += a;
        __syncthreads();
    }
    if (tid < NBK) {
        excl[tid] = sc[tid] - hv;
        cur[tid]  = sc[tid] - hv;
    }
    __syncthreads();
    for (int i = tid; i < cnt; i += 256) {
        int d = dst[e0 + i];
        int b = d >> 8;
        int pos = atomicAdd(&cur[b], 1);
        lp[pos] = (b << 24) | ((d & 255) << 16) | src[e0 + i];
    }
    __syncthreads();
    if (tid < NBK && hist[tid] > 0)
        gbase[tid] = atomicAdd(&bucket_cursor[tid], hist[tid]);
    __syncthreads();
    for (int i = tid; i < cnt; i += 256) {
        int p = lp[i];
        int b = (p >> 24) & 0xff;
        pairs[gbase[b] + (i - excl[b])] = p;
    }
}

__global__ __launch_bounds__(256) void k_passC(const int* __restrict__ pairs,
                                               const int* __restrict__ bucket_base,
                                               int* __restrict__ row_ptr,
                                               unsigned short* __restrict__ colu) {
    __shared__ int hist[256];
    __shared__ int cur[256];
    __shared__ int sc[256];
    int b = blockIdx.x;
    int tid = threadIdx.x;
    int v0 = b << 8;
    int e0 = bucket_base[b], e1 = bucket_base[b + 1];
    hist[tid] = 0;
    __syncthreads();
    for (int i = e0 + tid; i < e1; i += 256) atomicAdd(&hist[(pairs[i] >> 16) & 0xff], 1);
    __syncthreads();
    int hv = hist[tid];
    sc[tid] = hv;
    __syncthreads();
    for (int off = 1; off < 256; off <<= 1) {
        int a = (tid >= off) ? sc[tid - off] : 0;
        __syncthreads();
        sc[tid] += a;
        __syncthreads();
    }
    int base = e0 + sc[tid] - hv;
    int v = v0 + tid;
    if (v < N_NODES) row_ptr[v] = base;
    cur[tid] = base;
    __syncthreads();
    for (int i = e0 + tid; i < e1; i += 256) {
        int p = pairs[i];
        int pos = atomicAdd(&cur[(p >> 16) & 0xff], 1);
        colu[pos] = (unsigned short)(p & 0xffff);
    }
}

// ============ merged prep: pack Wl, pack Wproj (K padded to 64), cast X =====
// blocks [0,32): WlPack; [32,40): WprojPack; [40,...): Xb cast (grid-stride)
__global__ __launch_bounds__(256) void k_prep(const float* __restrict__ Wl,
                                              const float* __restrict__ Wproj,
                                              const float* __restrict__ X,
                                              unsigned short* __restrict__ WlPack,
                                              unsigned short* __restrict__ WprojPack,
                                              unsigned short* __restrict__ Xb) {
    int b = blockIdx.x;
    int tid = threadIdx.x;
    if (b < 32) {                       // WlPack: 8192 frags
        int i = b * 256 + tid;
        int kg = i >> 8, n = i & 255;
        short8v v;
#pragma unroll
        for (int j = 0; j < 8; j++) v[j] = (short)f2bf(Wl[(kg * 8 + j) * HIDDEN + n]);
        *(short8v*)(WlPack + (size_t)(kg * 256 + n) * 8) = v;
    } else if (b < 40) {                // WprojPack: kg in [0,8) => K 0..63, zero-pad k>=44
        int i = (b - 32) * 256 + tid;   // 2048 frags
        int kg = i >> 8, n = i & 255;
        short8v v;
#pragma unroll
        for (int j = 0; j < 8; j++) {
            int k = kg * 8 + j;
            v[j] = (k < IN_SIZE) ? (short)f2bf(Wproj[k * HIDDEN + n]) : (short)0;
        }
        *(short8v*)(WprojPack + (size_t)(kg * 256 + n) * 8) = v;
    } else {                            // Xb: N x XK bf16, cols 44..47 = 0
        const int TOT = N_NODES * XK;
        int id0 = (b - 40) * 2048 + tid;
#pragma unroll
        for (int j = 0; j < 8; j++) {
            int id = id0 + j * 256;
            if (id < TOT) {
                int row = id / XK, c = id % XK;
                Xb[id] = (c < IN_SIZE) ? f2bf(X[row * IN_SIZE + c]) : (unsigned short)0;
            }
        }
    }
}

// ====== fused layer 1: gather X -> MFMA(Wproj) -> MFMA(Wl) -> store+readout ==
// h1 = ((X[v] + mean X[u]) @ Wproj + bp*(1+[deg>0])) @ Wl + bl
#define TLS 264
#define K1S 72
__global__ __launch_bounds__(512, 8) void k_layer1(const unsigned short* __restrict__ Xb,
                                                   const int* __restrict__ row_ptr,
                                                   const unsigned short* __restrict__ colu,
                                                   const unsigned short* __restrict__ WprojPack,
                                                   const float* __restrict__ bp,
                                                   const unsigned short* __restrict__ WlPack,
                                                   const float* __restrict__ bl,
                                                   const int* __restrict__ gid,
                                                   unsigned short* __restrict__ hout,
                                                   float* __restrict__ GsumL) {
    __shared__ unsigned short tl[64 * TLS];    // 33792 B (t tile, then h1 tile)
    __shared__ unsigned short tl1[64 * K1S];   // 9216 B  (X-agg tile, K=64 padded)
    __shared__ float bpm[64];                  // bias multiplier 1/2 per row
    __shared__ int gl[64];
    int tid = threadIdx.x;
    int w = tid >> 6, lane = tid & 63, quad = lane >> 4, l16 = lane & 15;
    int m0 = blockIdx.x * 64;

    // ---- phase 1: gather X rows; lane = column (44 real + 4 pad of XK) ----
    for (int rr = 0; rr < 8; rr++) {
        int r = w * 8 + rr;
        int v = m0 + r;
        float a0 = 0.f, a1 = 0.f;
        float val = 0.f;
        float mul = 1.f;
        if (v < N_NODES) {
            int s = row_ptr[v], e = row_ptr[v + 1];
            if (lane < XK) {
                int i = s;
                for (; i + 4 <= e; i += 4) {
                    int u0 = colu[i], u1 = colu[i + 1];
                    int u2 = colu[i + 2], u3 = colu[i + 3];
                    a0 += bf2f(Xb[u0 * XK + lane]) + bf2f(Xb[u1 * XK + lane]);
                    a1 += bf2f(Xb[u2 * XK + lane]) + bf2f(Xb[u3 * XK + lane]);
                }
                for (; i < e; i++) a0 += bf2f(Xb[colu[i] * XK + lane]);
            }
            float inv = 0.f;
            if (e > s) { inv = 1.0f / (float)(e - s); mul = 2.f; }
            float self = (lane < XK) ? bf2f(Xb[(size_t)v * XK + lane]) : 0.f;
            val = self + inv * (a0 + a1);
        }
        tl1[r * K1S + lane] = (lane < XK) ? f2bf(val) : (unsigned short)0;
        if (lane == 0) bpm[r] = mul;
    }
    if (tid < 64) gl[tid] = (m0 + tid < N_NODES) ? gid[m0 + tid] : -1;
    __syncthreads();

    // ---- phase 2: MFMA stage 1 (A = tl1 64x64, B = WprojPack) ----
    int n0 = w * 32;
    f32x4 acc[4][2];
#pragma unroll
    for (int mt = 0; mt < 4; mt++) {
        acc[mt][0] = (f32x4){0.f, 0.f, 0.f, 0.f};
        acc[mt][1] = (f32x4){0.f, 0.f, 0.f, 0.f};
    }
#pragma unroll
    for (int ks = 0; ks < 2; ks++) {
        int kg = ks * 4 + quad;
        short8v bfr0 = *(const short8v*)(WprojPack + (size_t)(kg * 256 + n0 + l16) * 8);
        short8v bfr1 = *(const short8v*)(WprojPack + (size_t)(kg * 256 + n0 + 16 + l16) * 8);
#pragma unroll
        for (int mt = 0; mt < 4; mt++) {
            short8v afr = *(const short8v*)(tl1 + (mt * 16 + l16) * K1S + ks * 32 + quad * 8);
            acc[mt][0] = __builtin_amdgcn_mfma_f32_16x16x32_bf16(afr, bfr0, acc[mt][0], 0, 0, 0);
            acc[mt][1] = __builtin_amdgcn_mfma_f32_16x16x32_bf16(afr, bfr1, acc[mt][1], 0, 0, 0);
        }
    }
    // t tile -> tl (bf16), bias bp * bpm[row]
#pragma unroll
    for (int nt = 0; nt < 2; nt++) {
        int colg = n0 + nt * 16 + l16;
        float bb = bp[colg];
#pragma unroll
        for (int mt = 0; mt < 4; mt++)
#pragma unroll
            for (int r = 0; r < 4; r++) {
                int row = mt * 16 + quad * 4 + r;
                tl[row * TLS + colg] = f2bf(acc[mt][nt][r] + bb * bpm[row]);
            }
    }
    __syncthreads();

    // ---- phase 3: MFMA stage 2 (A = tl 64x256, B = WlPack) ----
#pragma unroll
    for (int mt = 0; mt < 4; mt++) {
        acc[mt][0] = (f32x4){0.f, 0.f, 0.f, 0.f};
        acc[mt][1] = (f32x4){0.f, 0.f, 0.f, 0.f};
    }
#pragma unroll
    for (int ks = 0; ks < 8; ks++) {
        int kg = ks * 4 + quad;
        short8v bfr0 = *(const short8v*)(WlPack + (size_t)(kg * 256 + n0 + l16) * 8);
        short8v bfr1 = *(const short8v*)(WlPack + (size_t)(kg * 256 + n0 + 16 + l16) * 8);
#pragma unroll
        for (int mt = 0; mt < 4; mt++) {
            short8v afr = *(const short8v*)(tl + (mt * 16 + l16) * TLS + ks * 32 + quad * 8);
            acc[mt][0] = __builtin_amdgcn_mfma_f32_16x16x32_bf16(afr, bfr0, acc[mt][0], 0, 0, 0);
            acc[mt][1] = __builtin_amdgcn_mfma_f32_16x16x32_bf16(afr, bfr1, acc[mt][1], 0, 0, 0);
        }
    }
    __syncthreads();  // A-frag reads complete before tile overwrite

    // ---- phase 4: epilogue -> bf16 h1 into tl ----
#pragma unroll
    for (int nt = 0; nt < 2; nt++) {
        int colg = n0 + nt * 16 + l16;
        float bb = bl[colg];
#pragma unroll
        for (int mt = 0; mt < 4; mt++)
#pragma unroll
            for (int r = 0; r < 4; r++)
                tl[(mt * 16 + quad * 4 + r) * TLS + colg] = f2bf(acc[mt][nt][r] + bb);
    }
    __syncthreads();

    // ---- phase 5a: coalesced global store ----
    for (int i = tid; i < 64 * 64; i += 512) {
        int r = i >> 6, c4 = i & 63;
        int v = m0 + r;
        if (v < N_NODES)
            ((ushort4*)hout)[(size_t)v * 64 + c4] = *(ushort4*)(tl + r * TLS + c4 * 4);
    }
    // ---- phase 5b: fused readout ----
    {
        int c = tid & 255;
        int r0 = (tid >> 8) * 32;
        float a2 = 0.f;
        int curg = gl[r0];
        for (int r = r0; r < r0 + 32; r++) {
            int g = gl[r];
            if (g < 0) break;
            if (g != curg) {
                atomicAdd(&GsumL[curg * HIDDEN + c], a2);
                a2 = 0.f;
                curg = g;
            }
            a2 += bf2f(tl[r * TLS + c]);
        }
        if (curg >= 0) atomicAdd(&GsumL[curg * HIDDEN + c], a2);
    }
}

// ====== fused layer (2,3): gather -> LDS -> MFMA -> store + readout =========
__global__ __launch_bounds__(512, 8) void k_layer(const unsigned short* __restrict__ h,
                                                  const int* __restrict__ row_ptr,
                                                  const unsigned short* __restrict__ colu,
                                                  const unsigned short* __restrict__ Wpack,
                                                  const float* __restrict__ bias,
                                                  const int* __restrict__ gid,
                                                  unsigned short* __restrict__ hout,
                                                  float* __restrict__ GsumL) {
    __shared__ unsigned short tl[64 * TLS];   // 33792 B
    __shared__ int gl[64];
    int tid = threadIdx.x;
    int w = tid >> 6, lane = tid & 63, quad = lane >> 4, l16 = lane & 15;
    int m0 = blockIdx.x * 64;

    const ushort4* hv = (const ushort4*)h;
    for (int rr = 0; rr < 8; rr++) {
        int r = w * 8 + rr;
        int v = m0 + r;
        float a0 = 0.f, a1 = 0.f, a2 = 0.f, a3 = 0.f;
        if (v < N_NODES) {
            int s = row_ptr[v], e = row_ptr[v + 1];
            int i = s;
            for (; i + 4 <= e; i += 4) {
                int u0 = colu[i], u1 = colu[i + 1], u2 = colu[i + 2], u3 = colu[i + 3];
                ushort4 p = hv[(size_t)u0 * 64 + lane];
                ushort4 q = hv[(size_t)u1 * 64 + lane];
                ushort4 x = hv[(size_t)u2 * 64 + lane];
                ushort4 y = hv[(size_t)u3 * 64 + lane];
                a0 += bf2f(p.x) + bf2f(q.x) + bf2f(x.x) + bf2f(y.x);
                a1 += bf2f(p.y) + bf2f(q.y) + bf2f(x.y) + bf2f(y.y);
                a2 += bf2f(p.z) + bf2f(q.z) + bf2f(x.z) + bf2f(y.z);
                a3 += bf2f(p.w) + bf2f(q.w) + bf2f(x.w) + bf2f(y.w);
            }
            for (; i < e; i++) {
                ushort4 p = hv[(size_t)colu[i] * 64 + lane];
                a0 += bf2f(p.x); a1 += bf2f(p.y); a2 += bf2f(p.z); a3 += bf2f(p.w);
            }
            float inv = (e > s) ? 1.0f / (float)(e - s) : 0.0f;
            ushort4 hs = hv[(size_t)v * 64 + lane];
            a0 = bf2f(hs.x) + inv * a0;
            a1 = bf2f(hs.y) + inv * a1;
            a2 = bf2f(hs.z) + inv * a2;
            a3 = bf2f(hs.w) + inv * a3;
        }
        ushort4 o;
        o.x = f2bf(a0); o.y = f2bf(a1); o.z = f2bf(a2); o.w = f2bf(a3);
        *(ushort4*)(tl + r * TLS + lane * 4) = o;
    }
    if (tid < 64) gl[tid] = (m0 + tid < N_NODES) ? gid[m0 + tid] : -1;
    __syncthreads();

    int n0 = w * 32;
    f32x4 acc[4][2];
#pragma unroll
    for (int mt = 0; mt < 4; mt++) {
        acc[mt][0] = (f32x4){0.f, 0.f, 0.f, 0.f};
        acc[mt][1] = (f32x4){0.f, 0.f, 0.f, 0.f};
    }
#pragma unroll
    for (int ks = 0; ks < 8; ks++) {
        int kg = ks * 4 + quad;
        short8v bfr0 = *(const short8v*)(Wpack + (size_t)(kg * 256 + n0 + l16) * 8);
        short8v bfr1 = *(const short8v*)(Wpack + (size_t)(kg * 256 + n0 + 16 + l16) * 8);
#pragma unroll
        for (int mt = 0; mt < 4; mt++) {
            short8v afr = *(const short8v*)(tl + (mt * 16 + l16) * TLS + ks * 32 + quad * 8);
            acc[mt][0] = __builtin_amdgcn_mfma_f32_16x16x32_bf16(afr, bfr0, acc[mt][0], 0, 0, 0);
            acc[mt][1] = __builtin_amdgcn_mfma_f32_16x16x32_bf16(afr, bfr1, acc[mt][1], 0, 0, 0);
        }
    }
    __syncthreads();

#pragma unroll
    for (int nt = 0; nt < 2; nt++) {
        int colg = n0 + nt * 16 + l16;
        float bb = bias[colg];
#pragma unroll
        for (int mt = 0; mt < 4; mt++)
#pragma unroll
            for (int r = 0; r < 4; r++)
                tl[(mt * 16 + quad * 4 + r) * TLS + colg] = f2bf(acc[mt][nt][r] + bb);
    }
    __syncthreads();

    for (int i = tid; i < 64 * 64; i += 512) {
        int r = i >> 6, c4 = i & 63;
        int v = m0 + r;
        if (v < N_NODES)
            ((ushort4*)hout)[(size_t)v * 64 + c4] = *(ushort4*)(tl + r * TLS + c4 * 4);
    }
    {
        int c = tid & 255;
        int r0 = (tid >> 8) * 32;
        float a2 = 0.f;
        int curg = gl[r0];
        for (int r = r0; r < r0 + 32; r++) {
            int g = gl[r];
            if (g < 0) break;
            if (g != curg) {
                atomicAdd(&GsumL[curg * HIDDEN + c], a2);
                a2 = 0.f;
                curg = g;
            }
            a2 += bf2f(tl[r * TLS + c]);
        }
        if (curg >= 0) atomicAdd(&GsumL[curg * HIDDEN + c], a2);
    }
}

// ================= out[g] = (concat gmean) @ W_out + b_out ==================
__global__ __launch_bounds__(256) void k_out(const float* __restrict__ Gsum,
                                             const int* __restrict__ gcnt,
                                             const float* __restrict__ Wout,
                                             const float* __restrict__ bout,
                                             float* __restrict__ out) {
    int g = blockIdx.x;
    int c = threadIdx.x;
    __shared__ float gm[HIDDEN * CONV_NUMS];
    float invc = 1.0f / fmaxf((float)gcnt[g], 1.0f);
    for (int i = c; i < HIDDEN * CONV_NUMS; i += 256) {
        int l = i >> 8;
        int k = i & 255;
        gm[i] = Gsum[(size_t)l * N_GRAPHS * HIDDEN + g * HIDDEN + k] * invc;
    }
    __syncthreads();
    float acc = bout[c];
    const float4* gm4 = (const float4*)gm;
    for (int k0 = 0; k0 < HIDDEN * CONV_NUMS; k0 += 4) {
        float4 gv = gm4[k0 >> 2];
        acc += gv.x * Wout[(k0 + 0) * HIDDEN + c];
        acc += gv.y * Wout[(k0 + 1) * HIDDEN + c];
        acc += gv.z * Wout[(k0 + 2) * HIDDEN + c];
        acc += gv.w * Wout[(k0 + 3) * HIDDEN + c];
    }
    out[g * HIDDEN + c] = acc;
}

extern "C" void kernel_launch(void* const* d_in, const int* in_sizes, int n_in,
                              void* d_out, int out_size, void* d_ws, size_t ws_size,
                              hipStream_t stream) {
    const float* X    = (const float*)d_in[0];
    const int*   src  = (const int*)d_in[1];
    const int*   dst  = (const int*)d_in[2];
    const int*   gid  = (const int*)d_in[3];
    const float* Wp   = (const float*)d_in[4];
    const float* bp   = (const float*)d_in[5];
    const float* Wl   = (const float*)d_in[6];
    const float* bl   = (const float*)d_in[7];
    const float* Wout = (const float*)d_in[8];
    const float* bout = (const float*)d_in[9];
    float* out = (float*)d_out;

    char* ws = (char*)d_ws;
    size_t off = 0;
    auto alloc = [&](size_t bytes) {
        char* p = ws + off;
        off += (bytes + 255) & ~size_t(255);
        return p;
    };
    unsigned short* h         = (unsigned short*)alloc(sizeof(short) * N_NODES * HIDDEN);
    unsigned short* t         = (unsigned short*)alloc(sizeof(short) * N_NODES * HIDDEN);
    unsigned short* WlPack    = (unsigned short*)alloc(sizeof(short) * HIDDEN * HIDDEN);
    unsigned short* WprojPack = (unsigned short*)alloc(sizeof(short) * 8 * 256 * 8);
    unsigned short* Xb        = (unsigned short*)alloc(sizeof(short) * N_NODES * XK);
    int*   pairs   = (int*)alloc(sizeof(int) * N_EDGES);
    unsigned short* colu = (unsigned short*)alloc(sizeof(short) * N_EDGES);
    int*   row_ptr = (int*)alloc(sizeof(int) * (N_NODES + 1));
    int*   bucket_base   = (int*)alloc(sizeof(int) * (NBK + 1));
    int*   bucket_cursor = (int*)alloc(sizeof(int) * NBK);
    // contiguous zero region: bucket_cnt | gcnt | Gsum  -> one memset
    char*  zero0 = ws + off;
    int*   bucket_cnt = (int*)alloc(sizeof(int) * NBK);
    int*   gcnt       = (int*)alloc(sizeof(int) * N_GRAPHS);
    float* Gsum       = (float*)alloc(sizeof(float) * CONV_NUMS * N_GRAPHS * HIDDEN);
    size_t zero_bytes = (size_t)((char*)(Gsum + CONV_NUMS * N_GRAPHS * HIDDEN) - zero0);

    hipMemsetAsync(zero0, 0, zero_bytes, stream);

    k_passA<<<512, 256, 0, stream>>>(dst, gid, bucket_cnt, gcnt);
    k_bscan<<<1, 256, 0, stream>>>(bucket_cnt, bucket_base, bucket_cursor, row_ptr);
    k_passB<<<(N_EDGES + BCH - 1) / BCH, 256, 0, stream>>>(src, dst, bucket_cursor, pairs);
    // prep overlaps nothing it depends on: needs only Wl/Wp/X
    {
        const int TOT = N_NODES * XK;
        int ncast = (TOT + 2047) / 2048;
        k_prep<<<40 + ncast, 256, 0, stream>>>(Wl, Wp, X, WlPack, WprojPack, Xb);
    }
    k_passC<<<NBK, 256, 0, stream>>>(pairs, bucket_base, row_ptr, colu);

    // layer 1 (fused proj + conv1 + readout)
    k_layer1<<<(N_NODES + 63) / 64, 512, 0, stream>>>(
        Xb, row_ptr, colu, WprojPack, bp, WlPack, bl, gid, h, Gsum);

    // layers 2,3
    unsigned short* cur = h;
    unsigned short* nxt = t;
    for (int l = 1; l < CONV_NUMS; l++) {
        k_layer<<<(N_NODES + 63) / 64, 512, 0, stream>>>(
            cur, row_ptr, colu, WlPack, bl, gid, nxt,
            Gsum + (size_t)l * N_GRAPHS * HIDDEN);
        unsigned short* tmp = cur; cur = nxt; nxt = tmp;
    }

    k_out<<<N_GRAPHS, 256, 0, stream>>>(Gsum, gcnt, Wout, bout, out);
}

// Round 8
// 452.824 us; speedup vs baseline: 1.3865x; 1.1842x over previous
//
#include <hip/hip_runtime.h>
#include <hip/hip_fp8.h>

#define N_NODES   50000
#define N_EDGES   1600000
#define N_GRAPHS  512
#define IN_SIZE   44
#define HIDDEN    256
#define CONV_NUMS 3
#define NBK       ((N_NODES + 255) / 256)   // 196 dst-buckets of 256 nodes
#define XK        48                        // padded K for X (44 -> 48, stride)

typedef __attribute__((ext_vector_type(8))) short short8v;   // 8 bf16 = 16 B
typedef __attribute__((ext_vector_type(4))) float f32x4;     // MFMA C/D frag

__device__ __forceinline__ float bf2f(unsigned short u) {
    return __uint_as_float(((unsigned int)u) << 16);
}
__device__ __forceinline__ unsigned short f2bf(float f) {
    unsigned int u = __float_as_uint(f);
    unsigned int r = (u + 0x7fffu + ((u >> 16) & 1u)) >> 16;  // RNE
    return (unsigned short)r;
}

// ---- fp8 e4m3 (OCP on gfx950) helpers: HW cvt with HIP-type fallback ----
#if __has_builtin(__builtin_amdgcn_cvt_f32_fp8)
template <int SEL>
__device__ __forceinline__ float fp8tof(unsigned int w) {
    return __builtin_amdgcn_cvt_f32_fp8((int)w, SEL);
}
#else
template <int SEL>
__device__ __forceinline__ float fp8tof(unsigned int w) {
    __hip_fp8_e4m3 q;
    q.__x = (__hip_fp8_storage_t)((w >> (SEL * 8)) & 0xff);
    return (float)q;
}
#endif

#if __has_builtin(__builtin_amdgcn_cvt_pk_fp8_f32)
__device__ __forceinline__ unsigned int pk4fp8(float f0, float f1, float f2, float f3) {
    int lo = __builtin_amdgcn_cvt_pk_fp8_f32(f0, f1, 0, false);
    return (unsigned int)__builtin_amdgcn_cvt_pk_fp8_f32(f2, f3, lo, true);
}
#else
__device__ __forceinline__ unsigned int pk4fp8(float f0, float f1, float f2, float f3) {
    __hip_fp8_e4m3 a(f0), b(f1), c(f2), d(f3);
    return (unsigned int)a.__x | ((unsigned int)b.__x << 8) |
           ((unsigned int)c.__x << 16) | ((unsigned int)d.__x << 24);
}
#endif

// ============================ graph build ===================================
__global__ __launch_bounds__(256) void k_passA(const int* __restrict__ dst,
                                               const int* __restrict__ gid,
                                               int* __restrict__ bucket_cnt,
                                               int* __restrict__ gcnt) {
    __shared__ int hb[NBK];
    __shared__ int hg[N_GRAPHS];
    int tid = threadIdx.x;
    for (int i = tid; i < NBK; i += 256) hb[i] = 0;
    for (int i = tid; i < N_GRAPHS; i += 256) hg[i] = 0;
    __syncthreads();
    int t = blockIdx.x * 256 + tid;
    int stride = gridDim.x * 256;
    for (int e = t; e < N_EDGES; e += stride) atomicAdd(&hb[dst[e] >> 8], 1);
    for (int v = t; v < N_NODES; v += stride) atomicAdd(&hg[gid[v]], 1);
    __syncthreads();
    for (int i = tid; i < NBK; i += 256) if (hb[i]) atomicAdd(&bucket_cnt[i], hb[i]);
    for (int i = tid; i < N_GRAPHS; i += 256) if (hg[i]) atomicAdd(&gcnt[i], hg[i]);
}

__global__ void k_bscan(const int* __restrict__ bucket_cnt, int* __restrict__ bucket_base,
                        int* __restrict__ bucket_cursor, int* __restrict__ row_ptr) {
    __shared__ int s[256];
    int t = threadIdx.x;
    int v = (t < NBK) ? bucket_cnt[t] : 0;
    s[t] = v;
    __syncthreads();
    for (int off = 1; off < 256; off <<= 1) {
        int a = (t >= off) ? s[t - off] : 0;
        __syncthreads();
        s[t] += a;
        __syncthreads();
    }
    if (t < NBK) {
        int base = s[t] - v;
        bucket_base[t] = base;
        bucket_cursor[t] = base;
    }
    if (t == 0) {
        bucket_base[NBK] = N_EDGES;
        row_ptr[N_NODES] = N_EDGES;
    }
}

#define BCH 4096
__global__ __launch_bounds__(256) void k_passB(const int* __restrict__ src,
                                               const int* __restrict__ dst,
                                               int* __restrict__ bucket_cursor,
                                               int* __restrict__ pairs) {
    __shared__ int hist[NBK];
    __shared__ int excl[NBK];
    __shared__ int cur[NBK];
    __shared__ int gbase[NBK];
    __shared__ int lp[BCH];
    __shared__ int sc[256];
    int tid = threadIdx.x;
    int e0 = blockIdx.x * BCH;
    int cnt = min(BCH, N_EDGES - e0);
    for (int i = tid; i < NBK; i += 256) hist[i] = 0;
    __syncthreads();
    for (int i = tid; i < cnt; i += 256) atomicAdd(&hist[dst[e0 + i] >> 8], 1);
    __syncthreads();
    int hv = (tid < NBK) ? hist[tid] : 0;
    sc[tid] = hv;
    __syncthreads();
    for (int off = 1; off < 256; off <<= 1) {
        int a = (tid >= off) ? sc[tid - off] : 0;
        __syncthreads();
        sc[tid] += a;
        __syncthreads();
    }
    if (tid < NBK) {
        excl[tid] = sc[tid] - hv;
        cur[tid]  = sc[tid] - hv;
    }
    __syncthreads();
    for (int i = tid; i < cnt; i += 256) {
        int d = dst[e0 + i];
        int b = d >> 8;
        int pos = atomicAdd(&cur[b], 1);
        lp[pos] = (b << 24) | ((d & 255) << 16) | src[e0 + i];
    }
    __syncthreads();
    if (tid < NBK && hist[tid] > 0)
        gbase[tid] = atomicAdd(&bucket_cursor[tid], hist[tid]);
    __syncthreads();
    for (int i = tid; i < cnt; i += 256) {
        int p = lp[i];
        int b = (p >> 24) & 0xff;
        pairs[gbase[b] + (i - excl[b])] = p;
    }
}

__global__ __launch_bounds__(256) void k_passC(const int* __restrict__ pairs,
                                               const int* __restrict__ bucket_base,
                                               int* __restrict__ row_ptr,
                                               unsigned short* __restrict__ colu) {
    __shared__ int hist[256];
    __shared__ int cur[256];
    __shared__ int sc[256];
    int b = blockIdx.x;
    int tid = threadIdx.x;
    int v0 = b << 8;
    int e0 = bucket_base[b], e1 = bucket_base[b + 1];
    hist[tid] = 0;
    __syncthreads();
    for (int i = e0 + tid; i < e1; i += 256) atomicAdd(&hist[(pairs[i] >> 16) & 0xff], 1);
    __syncthreads();
    int hv = hist[tid];
    sc[tid] = hv;
    __syncthreads();
    for (int off = 1; off < 256; off <<= 1) {
        int a = (tid >= off) ? sc[tid - off] : 0;
        __syncthreads();
        sc[tid] += a;
        __syncthreads();
    }
    int base = e0 + sc[tid] - hv;
    int v = v0 + tid;
    if (v < N_NODES) row_ptr[v] = base;
    cur[tid] = base;
    __syncthreads();
    for (int i = e0 + tid; i < e1; i += 256) {
        int p = pairs[i];
        int pos = atomicAdd(&cur[(p >> 16) & 0xff], 1);
        colu[pos] = (unsigned short)(p & 0xffff);
    }
}

// ============ merged prep: pack Wl, pack Wproj (K padded to 64), cast X =====
__global__ __launch_bounds__(256) void k_prep(const float* __restrict__ Wl,
                                              const float* __restrict__ Wproj,
                                              const float* __restrict__ X,
                                              unsigned short* __restrict__ WlPack,
                                              unsigned short* __restrict__ WprojPack,
                                              unsigned short* __restrict__ Xb) {
    int b = blockIdx.x;
    int tid = threadIdx.x;
    if (b < 32) {                       // WlPack: 8192 frags
        int i = b * 256 + tid;
        int kg = i >> 8, n = i & 255;
        short8v v;
#pragma unroll
        for (int j = 0; j < 8; j++) v[j] = (short)f2bf(Wl[(kg * 8 + j) * HIDDEN + n]);
        *(short8v*)(WlPack + (size_t)(kg * 256 + n) * 8) = v;
    } else if (b < 40) {                // WprojPack: kg in [0,8), zero-pad k>=44
        int i = (b - 32) * 256 + tid;
        int kg = i >> 8, n = i & 255;
        short8v v;
#pragma unroll
        for (int j = 0; j < 8; j++) {
            int k = kg * 8 + j;
            v[j] = (k < IN_SIZE) ? (short)f2bf(Wproj[k * HIDDEN + n]) : (short)0;
        }
        *(short8v*)(WprojPack + (size_t)(kg * 256 + n) * 8) = v;
    } else {                            // Xb: N x XK bf16, cols 44..47 = 0
        const int TOT = N_NODES * XK;
        int id0 = (b - 40) * 2048 + tid;
#pragma unroll
        for (int j = 0; j < 8; j++) {
            int id = id0 + j * 256;
            if (id < TOT) {
                int row = id / XK, c = id % XK;
                Xb[id] = (c < IN_SIZE) ? f2bf(X[row * IN_SIZE + c]) : (unsigned short)0;
            }
        }
    }
}

// ====== fused layer 1: gather X -> MFMA(Wproj) -> MFMA(Wl) -> store+readout ==
#define TLS 264
#define K1S 72
__global__ __launch_bounds__(512, 8) void k_layer1(const unsigned short* __restrict__ Xb,
                                                   const int* __restrict__ row_ptr,
                                                   const unsigned short* __restrict__ colu,
                                                   const unsigned short* __restrict__ WprojPack,
                                                   const float* __restrict__ bp,
                                                   const unsigned short* __restrict__ WlPack,
                                                   const float* __restrict__ bl,
                                                   const int* __restrict__ gid,
                                                   unsigned short* __restrict__ hout,
                                                   unsigned char* __restrict__ hout8,
                                                   float* __restrict__ GsumL) {
    __shared__ unsigned short tl[64 * TLS];
    __shared__ unsigned short tl1[64 * K1S];
    __shared__ float bpm[64];
    __shared__ int gl[64];
    int tid = threadIdx.x;
    int w = tid >> 6, lane = tid & 63, quad = lane >> 4, l16 = lane & 15;
    int m0 = blockIdx.x * 64;

    // ---- phase 1: gather X rows; lane = column ----
    for (int rr = 0; rr < 8; rr++) {
        int r = w * 8 + rr;
        int v = m0 + r;
        float a0 = 0.f, a1 = 0.f;
        float val = 0.f;
        float mul = 1.f;
        if (v < N_NODES) {
            int s = row_ptr[v], e = row_ptr[v + 1];
            if (lane < XK) {
                int i = s;
                for (; i + 4 <= e; i += 4) {
                    int u0 = colu[i], u1 = colu[i + 1];
                    int u2 = colu[i + 2], u3 = colu[i + 3];
                    a0 += bf2f(Xb[u0 * XK + lane]) + bf2f(Xb[u1 * XK + lane]);
                    a1 += bf2f(Xb[u2 * XK + lane]) + bf2f(Xb[u3 * XK + lane]);
                }
                for (; i < e; i++) a0 += bf2f(Xb[colu[i] * XK + lane]);
            }
            float inv = 0.f;
            if (e > s) { inv = 1.0f / (float)(e - s); mul = 2.f; }
            float self = (lane < XK) ? bf2f(Xb[(size_t)v * XK + lane]) : 0.f;
            val = self + inv * (a0 + a1);
        }
        tl1[r * K1S + lane] = (lane < XK) ? f2bf(val) : (unsigned short)0;
        if (lane == 0) bpm[r] = mul;
    }
    if (tid < 64) gl[tid] = (m0 + tid < N_NODES) ? gid[m0 + tid] : -1;
    __syncthreads();

    // ---- phase 2: MFMA stage 1 ----
    int n0 = w * 32;
    f32x4 acc[4][2];
#pragma unroll
    for (int mt = 0; mt < 4; mt++) {
        acc[mt][0] = (f32x4){0.f, 0.f, 0.f, 0.f};
        acc[mt][1] = (f32x4){0.f, 0.f, 0.f, 0.f};
    }
#pragma unroll
    for (int ks = 0; ks < 2; ks++) {
        int kg = ks * 4 + quad;
        short8v bfr0 = *(const short8v*)(WprojPack + (size_t)(kg * 256 + n0 + l16) * 8);
        short8v bfr1 = *(const short8v*)(WprojPack + (size_t)(kg * 256 + n0 + 16 + l16) * 8);
#pragma unroll
        for (int mt = 0; mt < 4; mt++) {
            short8v afr = *(const short8v*)(tl1 + (mt * 16 + l16) * K1S + ks * 32 + quad * 8);
            acc[mt][0] = __builtin_amdgcn_mfma_f32_16x16x32_bf16(afr, bfr0, acc[mt][0], 0, 0, 0);
            acc[mt][1] = __builtin_amdgcn_mfma_f32_16x16x32_bf16(afr, bfr1, acc[mt][1], 0, 0, 0);
        }
    }
#pragma unroll
    for (int nt = 0; nt < 2; nt++) {
        int colg = n0 + nt * 16 + l16;
        float bb = bp[colg];
#pragma unroll
        for (int mt = 0; mt < 4; mt++)
#pragma unroll
            for (int r = 0; r < 4; r++) {
                int row = mt * 16 + quad * 4 + r;
                tl[row * TLS + colg] = f2bf(acc[mt][nt][r] + bb * bpm[row]);
            }
    }
    __syncthreads();

    // ---- phase 3: MFMA stage 2 ----
#pragma unroll
    for (int mt = 0; mt < 4; mt++) {
        acc[mt][0] = (f32x4){0.f, 0.f, 0.f, 0.f};
        acc[mt][1] = (f32x4){0.f, 0.f, 0.f, 0.f};
    }
#pragma unroll
    for (int ks = 0; ks < 8; ks++) {
        int kg = ks * 4 + quad;
        short8v bfr0 = *(const short8v*)(WlPack + (size_t)(kg * 256 + n0 + l16) * 8);
        short8v bfr1 = *(const short8v*)(WlPack + (size_t)(kg * 256 + n0 + 16 + l16) * 8);
#pragma unroll
        for (int mt = 0; mt < 4; mt++) {
            short8v afr = *(const short8v*)(tl + (mt * 16 + l16) * TLS + ks * 32 + quad * 8);
            acc[mt][0] = __builtin_amdgcn_mfma_f32_16x16x32_bf16(afr, bfr0, acc[mt][0], 0, 0, 0);
            acc[mt][1] = __builtin_amdgcn_mfma_f32_16x16x32_bf16(afr, bfr1, acc[mt][1], 0, 0, 0);
        }
    }
    __syncthreads();

    // ---- phase 4: epilogue ----
#pragma unroll
    for (int nt = 0; nt < 2; nt++) {
        int colg = n0 + nt * 16 + l16;
        float bb = bl[colg];
#pragma unroll
        for (int mt = 0; mt < 4; mt++)
#pragma unroll
            for (int r = 0; r < 4; r++)
                tl[(mt * 16 + quad * 4 + r) * TLS + colg] = f2bf(acc[mt][nt][r] + bb);
    }
    __syncthreads();

    // ---- phase 5a: coalesced stores (bf16 + fp8 mirror) ----
    for (int i = tid; i < 64 * 64; i += 512) {
        int r = i >> 6, c4 = i & 63;
        int v = m0 + r;
        if (v < N_NODES) {
            ushort4 q = *(ushort4*)(tl + r * TLS + c4 * 4);
            ((ushort4*)hout)[(size_t)v * 64 + c4] = q;
            ((unsigned int*)hout8)[(size_t)v * 64 + c4] =
                pk4fp8(bf2f(q.x), bf2f(q.y), bf2f(q.z), bf2f(q.w));
        }
    }
    // ---- phase 5b: fused readout ----
    {
        int c = tid & 255;
        int r0 = (tid >> 8) * 32;
        float a2 = 0.f;
        int curg = gl[r0];
        for (int r = r0; r < r0 + 32; r++) {
            int g = gl[r];
            if (g < 0) break;
            if (g != curg) {
                atomicAdd(&GsumL[curg * HIDDEN + c], a2);
                a2 = 0.f;
                curg = g;
            }
            a2 += bf2f(tl[r * TLS + c]);
        }
        if (curg >= 0) atomicAdd(&GsumL[curg * HIDDEN + c], a2);
    }
}

// ====== fused layer (2,3): fp8 gather -> MFMA -> store + readout ============
// Gather source = fp8 mirror h8 (12.8 MB table, 4 B/lane); self-term = bf16 h.
__global__ __launch_bounds__(512, 8) void k_layer(const unsigned short* __restrict__ h,
                                                  const unsigned char* __restrict__ h8,
                                                  const int* __restrict__ row_ptr,
                                                  const unsigned short* __restrict__ colu,
                                                  const unsigned short* __restrict__ Wpack,
                                                  const float* __restrict__ bias,
                                                  const int* __restrict__ gid,
                                                  unsigned short* __restrict__ hout,
                                                  unsigned char* __restrict__ hout8,
                                                  int write8,
                                                  float* __restrict__ GsumL) {
    __shared__ unsigned short tl[64 * TLS];   // 33792 B
    __shared__ int gl[64];
    int tid = threadIdx.x;
    int w = tid >> 6, lane = tid & 63, quad = lane >> 4, l16 = lane & 15;
    int m0 = blockIdx.x * 64;

    // ---- phase 1: fp8 gather + mean into LDS tile ----
    const unsigned int* h8v = (const unsigned int*)h8;   // 4 fp8 per lane (4 B)
    const ushort4* hv = (const ushort4*)h;
    for (int rr = 0; rr < 8; rr++) {
        int r = w * 8 + rr;
        int v = m0 + r;
        float a0 = 0.f, a1 = 0.f, a2 = 0.f, a3 = 0.f;
        if (v < N_NODES) {
            int s = row_ptr[v], e = row_ptr[v + 1];
            int i = s;
            for (; i + 4 <= e; i += 4) {
                int u0 = colu[i], u1 = colu[i + 1], u2 = colu[i + 2], u3 = colu[i + 3];
                unsigned int p = h8v[(size_t)u0 * 64 + lane];
                unsigned int q = h8v[(size_t)u1 * 64 + lane];
                unsigned int x = h8v[(size_t)u2 * 64 + lane];
                unsigned int y = h8v[(size_t)u3 * 64 + lane];
                a0 += fp8tof<0>(p) + fp8tof<0>(q) + fp8tof<0>(x) + fp8tof<0>(y);
                a1 += fp8tof<1>(p) + fp8tof<1>(q) + fp8tof<1>(x) + fp8tof<1>(y);
                a2 += fp8tof<2>(p) + fp8tof<2>(q) + fp8tof<2>(x) + fp8tof<2>(y);
                a3 += fp8tof<3>(p) + fp8tof<3>(q) + fp8tof<3>(x) + fp8tof<3>(y);
            }
            for (; i < e; i++) {
                unsigned int p = h8v[(size_t)colu[i] * 64 + lane];
                a0 += fp8tof<0>(p); a1 += fp8tof<1>(p);
                a2 += fp8tof<2>(p); a3 += fp8tof<3>(p);
            }
            float inv = (e > s) ? 1.0f / (float)(e - s) : 0.0f;
            ushort4 hs = hv[(size_t)v * 64 + lane];   // self-term bf16
            a0 = bf2f(hs.x) + inv * a0;
            a1 = bf2f(hs.y) + inv * a1;
            a2 = bf2f(hs.z) + inv * a2;
            a3 = bf2f(hs.w) + inv * a3;
        }
        ushort4 o;
        o.x = f2bf(a0); o.y = f2bf(a1); o.z = f2bf(a2); o.w = f2bf(a3);
        *(ushort4*)(tl + r * TLS + lane * 4) = o;
    }
    if (tid < 64) gl[tid] = (m0 + tid < N_NODES) ? gid[m0 + tid] : -1;
    __syncthreads();

    // ---- phase 2: MFMA ----
    int n0 = w * 32;
    f32x4 acc[4][2];
#pragma unroll
    for (int mt = 0; mt < 4; mt++) {
        acc[mt][0] = (f32x4){0.f, 0.f, 0.f, 0.f};
        acc[mt][1] = (f32x4){0.f, 0.f, 0.f, 0.f};
    }
#pragma unroll
    for (int ks = 0; ks < 8; ks++) {
        int kg = ks * 4 + quad;
        short8v bfr0 = *(const short8v*)(Wpack + (size_t)(kg * 256 + n0 + l16) * 8);
        short8v bfr1 = *(const short8v*)(Wpack + (size_t)(kg * 256 + n0 + 16 + l16) * 8);
#pragma unroll
        for (int mt = 0; mt < 4; mt++) {
            short8v afr = *(const short8v*)(tl + (mt * 16 + l16) * TLS + ks * 32 + quad * 8);
            acc[mt][0] = __builtin_amdgcn_mfma_f32_16x16x32_bf16(afr, bfr0, acc[mt][0], 0, 0, 0);
            acc[mt][1] = __builtin_amdgcn_mfma_f32_16x16x32_bf16(afr, bfr1, acc[mt][1], 0, 0, 0);
        }
    }
    __syncthreads();

    // ---- phase 3: epilogue ----
#pragma unroll
    for (int nt = 0; nt < 2; nt++) {
        int colg = n0 + nt * 16 + l16;
        float bb = bias[colg];
#pragma unroll
        for (int mt = 0; mt < 4; mt++)
#pragma unroll
            for (int r = 0; r < 4; r++)
                tl[(mt * 16 + quad * 4 + r) * TLS + colg] = f2bf(acc[mt][nt][r] + bb);
    }
    __syncthreads();

    // ---- phase 4a: coalesced stores (bf16 + optional fp8 mirror) ----
    for (int i = tid; i < 64 * 64; i += 512) {
        int r = i >> 6, c4 = i & 63;
        int v = m0 + r;
        if (v < N_NODES) {
            ushort4 q = *(ushort4*)(tl + r * TLS + c4 * 4);
            ((ushort4*)hout)[(size_t)v * 64 + c4] = q;
            if (write8)
                ((unsigned int*)hout8)[(size_t)v * 64 + c4] =
                    pk4fp8(bf2f(q.x), bf2f(q.y), bf2f(q.z), bf2f(q.w));
        }
    }
    // ---- phase 4b: fused readout ----
    {
        int c = tid & 255;
        int r0 = (tid >> 8) * 32;
        float a2 = 0.f;
        int curg = gl[r0];
        for (int r = r0; r < r0 + 32; r++) {
            int g = gl[r];
            if (g < 0) break;
            if (g != curg) {
                atomicAdd(&GsumL[curg * HIDDEN + c], a2);
                a2 = 0.f;
                curg = g;
            }
            a2 += bf2f(tl[r * TLS + c]);
        }
        if (curg >= 0) atomicAdd(&GsumL[curg * HIDDEN + c], a2);
    }
}

// ================= out[g] = (concat gmean) @ W_out + b_out ==================
__global__ __launch_bounds__(256) void k_out(const float* __restrict__ Gsum,
                                             const int* __restrict__ gcnt,
                                             const float* __restrict__ Wout,
                                             const float* __restrict__ bout,
                                             float* __restrict__ out) {
    int g = blockIdx.x;
    int c = threadIdx.x;
    __shared__ float gm[HIDDEN * CONV_NUMS];
    float invc = 1.0f / fmaxf((float)gcnt[g], 1.0f);
    for (int i = c; i < HIDDEN * CONV_NUMS; i += 256) {
        int l = i >> 8;
        int k = i & 255;
        gm[i] = Gsum[(size_t)l * N_GRAPHS * HIDDEN + g * HIDDEN + k] * invc;
    }
    __syncthreads();
    float acc = bout[c];
    const float4* gm4 = (const float4*)gm;
    for (int k0 = 0; k0 < HIDDEN * CONV_NUMS; k0 += 4) {
        float4 gv = gm4[k0 >> 2];
        acc += gv.x * Wout[(k0 + 0) * HIDDEN + c];
        acc += gv.y * Wout[(k0 + 1) * HIDDEN + c];
        acc += gv.z * Wout[(k0 + 2) * HIDDEN + c];
        acc += gv.w * Wout[(k0 + 3) * HIDDEN + c];
    }
    out[g * HIDDEN + c] = acc;
}

extern "C" void kernel_launch(void* const* d_in, const int* in_sizes, int n_in,
                              void* d_out, int out_size, void* d_ws, size_t ws_size,
                              hipStream_t stream) {
    const float* X    = (const float*)d_in[0];
    const int*   src  = (const int*)d_in[1];
    const int*   dst  = (const int*)d_in[2];
    const int*   gid  = (const int*)d_in[3];
    const float* Wp   = (const float*)d_in[4];
    const float* bp   = (const float*)d_in[5];
    const float* Wl   = (const float*)d_in[6];
    const float* bl   = (const float*)d_in[7];
    const float* Wout = (const float*)d_in[8];
    const float* bout = (const float*)d_in[9];
    float* out = (float*)d_out;

    char* ws = (char*)d_ws;
    size_t off = 0;
    auto alloc = [&](size_t bytes) {
        char* p = ws + off;
        off += (bytes + 255) & ~size_t(255);
        return p;
    };
    unsigned short* h         = (unsigned short*)alloc(sizeof(short) * N_NODES * HIDDEN);
    unsigned short* t         = (unsigned short*)alloc(sizeof(short) * N_NODES * HIDDEN);
    unsigned char*  h8a       = (unsigned char*)alloc((size_t)N_NODES * HIDDEN);
    unsigned char*  h8b       = (unsigned char*)alloc((size_t)N_NODES * HIDDEN);
    unsigned short* WlPack    = (unsigned short*)alloc(sizeof(short) * HIDDEN * HIDDEN);
    unsigned short* WprojPack = (unsigned short*)alloc(sizeof(short) * 8 * 256 * 8);
    unsigned short* Xb        = (unsigned short*)alloc(sizeof(short) * N_NODES * XK);
    int*   pairs   = (int*)alloc(sizeof(int) * N_EDGES);
    unsigned short* colu = (unsigned short*)alloc(sizeof(short) * N_EDGES);
    int*   row_ptr = (int*)alloc(sizeof(int) * (N_NODES + 1));
    int*   bucket_base   = (int*)alloc(sizeof(int) * (NBK + 1));
    int*   bucket_cursor = (int*)alloc(sizeof(int) * NBK);
    // contiguous zero region: bucket_cnt | gcnt | Gsum  -> one memset
    char*  zero0 = ws + off;
    int*   bucket_cnt = (int*)alloc(sizeof(int) * NBK);
    int*   gcnt       = (int*)alloc(sizeof(int) * N_GRAPHS);
    float* Gsum       = (float*)alloc(sizeof(float) * CONV_NUMS * N_GRAPHS * HIDDEN);
    size_t zero_bytes = (size_t)((char*)(Gsum + CONV_NUMS * N_GRAPHS * HIDDEN) - zero0);

    hipMemsetAsync(zero0, 0, zero_bytes, stream);

    k_passA<<<512, 256, 0, stream>>>(dst, gid, bucket_cnt, gcnt);
    k_bscan<<<1, 256, 0, stream>>>(bucket_cnt, bucket_base, bucket_cursor, row_ptr);
    k_passB<<<(N_EDGES + BCH - 1) / BCH, 256, 0, stream>>>(src, dst, bucket_cursor, pairs);
    {
        const int TOT = N_NODES * XK;
        int ncast = (TOT + 2047) / 2048;
        k_prep<<<40 + ncast, 256, 0, stream>>>(Wl, Wp, X, WlPack, WprojPack, Xb);
    }
    k_passC<<<NBK, 256, 0, stream>>>(pairs, bucket_base, row_ptr, colu);

    // layer 1 (fused proj + conv1 + readout); writes bf16 h + fp8 mirror h8a
    k_layer1<<<(N_NODES + 63) / 64, 512, 0, stream>>>(
        Xb, row_ptr, colu, WprojPack, bp, WlPack, bl, gid, h, h8a, Gsum);

    // layer 2: gather fp8(h8a), self bf16 h -> t + h8b
    k_layer<<<(N_NODES + 63) / 64, 512, 0, stream>>>(
        h, h8a, row_ptr, colu, WlPack, bl, gid, t, h8b, 1,
        Gsum + (size_t)1 * N_GRAPHS * HIDDEN);

    // layer 3: gather fp8(h8b), self bf16 t -> h (no fp8 mirror needed)
    k_layer<<<(N_NODES + 63) / 64, 512, 0, stream>>>(
        t, h8b, row_ptr, colu, WlPack, bl, gid, h, h8a, 0,
        Gsum + (size_t)2 * N_GRAPHS * HIDDEN);

    k_out<<<N_GRAPHS, 256, 0, stream>>>(Gsum, gcnt, Wout, bout, out);
}

// Round 9
// 366.153 us; speedup vs baseline: 1.7147x; 1.2367x over previous
//
#include <hip/hip_runtime.h>
#include <hip/hip_fp8.h>

#define N_NODES   50000
#define N_EDGES   1600000
#define N_GRAPHS  512
#define IN_SIZE   44
#define HIDDEN    256
#define CONV_NUMS 3
#define NBK       ((N_NODES + 255) / 256)   // 196 dst-buckets of 256 nodes
#define XK        48                        // padded K for X (44 -> 48, stride)

typedef __attribute__((ext_vector_type(8))) short short8v;   // 8 bf16 = 16 B
typedef __attribute__((ext_vector_type(4))) float f32x4;     // MFMA C/D frag

__device__ __forceinline__ float bf2f(unsigned short u) {
    return __uint_as_float(((unsigned int)u) << 16);
}
__device__ __forceinline__ unsigned short f2bf(float f) {
    unsigned int u = __float_as_uint(f);
    unsigned int r = (u + 0x7fffu + ((u >> 16) & 1u)) >> 16;  // RNE
    return (unsigned short)r;
}

// ---- fp8 e4m3 (OCP on gfx950) helpers: HW cvt with HIP-type fallback ----
#if __has_builtin(__builtin_amdgcn_cvt_f32_fp8)
template <int SEL>
__device__ __forceinline__ float fp8tof(unsigned int w) {
    return __builtin_amdgcn_cvt_f32_fp8((int)w, SEL);
}
#else
template <int SEL>
__device__ __forceinline__ float fp8tof(unsigned int w) {
    __hip_fp8_e4m3 q;
    q.__x = (__hip_fp8_storage_t)((w >> (SEL * 8)) & 0xff);
    return (float)q;
}
#endif

#if __has_builtin(__builtin_amdgcn_cvt_pk_fp8_f32)
__device__ __forceinline__ unsigned int pk4fp8(float f0, float f1, float f2, float f3) {
    int lo = __builtin_amdgcn_cvt_pk_fp8_f32(f0, f1, 0, false);
    return (unsigned int)__builtin_amdgcn_cvt_pk_fp8_f32(f2, f3, lo, true);
}
#else
__device__ __forceinline__ unsigned int pk4fp8(float f0, float f1, float f2, float f3) {
    __hip_fp8_e4m3 a(f0), b(f1), c(f2), d(f3);
    return (unsigned int)a.__x | ((unsigned int)b.__x << 8) |
           ((unsigned int)c.__x << 16) | ((unsigned int)d.__x << 24);
}
#endif

// ============================ graph build ===================================
__global__ __launch_bounds__(256) void k_passA(const int* __restrict__ dst,
                                               const int* __restrict__ gid,
                                               int* __restrict__ bucket_cnt,
                                               int* __restrict__ gcnt) {
    __shared__ int hb[NBK];
    __shared__ int hg[N_GRAPHS];
    int tid = threadIdx.x;
    for (int i = tid; i < NBK; i += 256) hb[i] = 0;
    for (int i = tid; i < N_GRAPHS; i += 256) hg[i] = 0;
    __syncthreads();
    int t = blockIdx.x * 256 + tid;
    int stride = gridDim.x * 256;
    for (int e = t; e < N_EDGES; e += stride) atomicAdd(&hb[dst[e] >> 8], 1);
    for (int v = t; v < N_NODES; v += stride) atomicAdd(&hg[gid[v]], 1);
    __syncthreads();
    for (int i = tid; i < NBK; i += 256) if (hb[i]) atomicAdd(&bucket_cnt[i], hb[i]);
    for (int i = tid; i < N_GRAPHS; i += 256) if (hg[i]) atomicAdd(&gcnt[i], hg[i]);
}

__global__ void k_bscan(const int* __restrict__ bucket_cnt, int* __restrict__ bucket_base,
                        int* __restrict__ bucket_cursor, int* __restrict__ row_ptr) {
    __shared__ int s[256];
    int t = threadIdx.x;
    int v = (t < NBK) ? bucket_cnt[t] : 0;
    s[t] = v;
    __syncthreads();
    for (int off = 1; off < 256; off <<= 1) {
        int a = (t >= off) ? s[t - off] : 0;
        __syncthreads();
        s[t] += a;
        __syncthreads();
    }
    if (t < NBK) {
        int base = s[t] - v;
        bucket_base[t] = base;
        bucket_cursor[t] = base;
    }
    if (t == 0) {
        bucket_base[NBK] = N_EDGES;
        row_ptr[N_NODES] = N_EDGES;
    }
}

#define BCH 4096
__global__ __launch_bounds__(256) void k_passB(const int* __restrict__ src,
                                               const int* __restrict__ dst,
                                               int* __restrict__ bucket_cursor,
                                               int* __restrict__ pairs) {
    __shared__ int hist[NBK];
    __shared__ int excl[NBK];
    __shared__ int cur[NBK];
    __shared__ int gbase[NBK];
    __shared__ int lp[BCH];
    __shared__ int sc[256];
    int tid = threadIdx.x;
    int e0 = blockIdx.x * BCH;
    int cnt = min(BCH, N_EDGES - e0);
    for (int i = tid; i < NBK; i += 256) hist[i] = 0;
    __syncthreads();
    for (int i = tid; i < cnt; i += 256) atomicAdd(&hist[dst[e0 + i] >> 8], 1);
    __syncthreads();
    int hv = (tid < NBK) ? hist[tid] : 0;
    sc[tid] = hv;
    __syncthreads();
    for (int off = 1; off < 256; off <<= 1) {
        int a = (tid >= off) ? sc[tid - off] : 0;
        __syncthreads();
        sc[tid] += a;
        __syncthreads();
    }
    if (tid < NBK) {
        excl[tid] = sc[tid] - hv;
        cur[tid]  = sc[tid] - hv;
    }
    __syncthreads();
    for (int i = tid; i < cnt; i += 256) {
        int d = dst[e0 + i];
        int b = d >> 8;
        int pos = atomicAdd(&cur[b], 1);
        lp[pos] = (b << 24) | ((d & 255) << 16) | src[e0 + i];
    }
    __syncthreads();
    if (tid < NBK && hist[tid] > 0)
        gbase[tid] = atomicAdd(&bucket_cursor[tid], hist[tid]);
    __syncthreads();
    for (int i = tid; i < cnt; i += 256) {
        int p = lp[i];
        int b = (p >> 24) & 0xff;
        pairs[gbase[b] + (i - excl[b])] = p;
    }
}

__global__ __launch_bounds__(256) void k_passC(const int* __restrict__ pairs,
                                               const int* __restrict__ bucket_base,
                                               int* __restrict__ row_ptr,
                                               unsigned short* __restrict__ colu) {
    __shared__ int hist[256];
    __shared__ int cur[256];
    __shared__ int sc[256];
    int b = blockIdx.x;
    int tid = threadIdx.x;
    int v0 = b << 8;
    int e0 = bucket_base[b], e1 = bucket_base[b + 1];
    hist[tid] = 0;
    __syncthreads();
    for (int i = e0 + tid; i < e1; i += 256) atomicAdd(&hist[(pairs[i] >> 16) & 0xff], 1);
    __syncthreads();
    int hv = hist[tid];
    sc[tid] = hv;
    __syncthreads();
    for (int off = 1; off < 256; off <<= 1) {
        int a = (tid >= off) ? sc[tid - off] : 0;
        __syncthreads();
        sc[tid] += a;
        __syncthreads();
    }
    int base = e0 + sc[tid] - hv;
    int v = v0 + tid;
    if (v < N_NODES) row_ptr[v] = base;
    cur[tid] = base;
    __syncthreads();
    for (int i = e0 + tid; i < e1; i += 256) {
        int p = pairs[i];
        int pos = atomicAdd(&cur[(p >> 16) & 0xff], 1);
        colu[pos] = (unsigned short)(p & 0xffff);
    }
}

// ============ merged prep: pack Wl, pack Wproj (K padded to 64), cast X =====
__global__ __launch_bounds__(256) void k_prep(const float* __restrict__ Wl,
                                              const float* __restrict__ Wproj,
                                              const float* __restrict__ X,
                                              unsigned short* __restrict__ WlPack,
                                              unsigned short* __restrict__ WprojPack,
                                              unsigned short* __restrict__ Xb) {
    int b = blockIdx.x;
    int tid = threadIdx.x;
    if (b < 32) {                       // WlPack: 8192 frags
        int i = b * 256 + tid;
        int kg = i >> 8, n = i & 255;
        short8v v;
#pragma unroll
        for (int j = 0; j < 8; j++) v[j] = (short)f2bf(Wl[(kg * 8 + j) * HIDDEN + n]);
        *(short8v*)(WlPack + (size_t)(kg * 256 + n) * 8) = v;
    } else if (b < 40) {                // WprojPack: kg in [0,8), zero-pad k>=44
        int i = (b - 32) * 256 + tid;
        int kg = i >> 8, n = i & 255;
        short8v v;
#pragma unroll
        for (int j = 0; j < 8; j++) {
            int k = kg * 8 + j;
            v[j] = (k < IN_SIZE) ? (short)f2bf(Wproj[k * HIDDEN + n]) : (short)0;
        }
        *(short8v*)(WprojPack + (size_t)(kg * 256 + n) * 8) = v;
    } else {                            // Xb: N x XK bf16, cols 44..47 = 0
        const int TOT = N_NODES * XK;
        int id0 = (b - 40) * 2048 + tid;
#pragma unroll
        for (int j = 0; j < 8; j++) {
            int id = id0 + j * 256;
            if (id < TOT) {
                int row = id / XK, c = id % XK;
                Xb[id] = (c < IN_SIZE) ? f2bf(X[row * IN_SIZE + c]) : (unsigned short)0;
            }
        }
    }
}

// ====== fused layer 1: gather X -> MFMA(Wproj) -> MFMA(Wl) -> store+readout ==
// tl1 (stage-1 A-tile) overlays tl: stage-1 MFMA reads complete before the
// stage-1 epilogue writes tl (extra barrier). LDS = 34.3 KB -> 4 blocks/CU.
#define TLS 264
#define K1S 72
__global__ __launch_bounds__(512, 8) void k_layer1(const unsigned short* __restrict__ Xb,
                                                   const int* __restrict__ row_ptr,
                                                   const unsigned short* __restrict__ colu,
                                                   const unsigned short* __restrict__ WprojPack,
                                                   const float* __restrict__ bp,
                                                   const unsigned short* __restrict__ WlPack,
                                                   const float* __restrict__ bl,
                                                   const int* __restrict__ gid,
                                                   unsigned short* __restrict__ hout,
                                                   unsigned char* __restrict__ hout8,
                                                   float* __restrict__ GsumL) {
    __shared__ unsigned short tl[64 * TLS];
    unsigned short* tl1 = tl;          // overlay: 64*K1S = 4608 shorts << 64*TLS
    __shared__ float bpm[64];
    __shared__ int gl[64];
    int tid = threadIdx.x;
    int w = tid >> 6, lane = tid & 63, quad = lane >> 4, l16 = lane & 15;
    int m0 = blockIdx.x * 64;

    // ---- phase 1: gather X rows; lane = column; 8 loads in flight ----
    for (int rr = 0; rr < 8; rr++) {
        int r = w * 8 + rr;
        int v = m0 + r;
        float a0 = 0.f, a1 = 0.f;
        float val = 0.f;
        float mul = 1.f;
        if (v < N_NODES) {
            int s = row_ptr[v], e = row_ptr[v + 1];
            if (lane < XK) {
                int i = s;
                for (; i + 8 <= e; i += 8) {
                    int u0 = colu[i],     u1 = colu[i + 1];
                    int u2 = colu[i + 2], u3 = colu[i + 3];
                    int u4 = colu[i + 4], u5 = colu[i + 5];
                    int u6 = colu[i + 6], u7 = colu[i + 7];
                    float t0 = bf2f(Xb[u0 * XK + lane]);
                    float t1 = bf2f(Xb[u1 * XK + lane]);
                    float t2 = bf2f(Xb[u2 * XK + lane]);
                    float t3 = bf2f(Xb[u3 * XK + lane]);
                    float t4 = bf2f(Xb[u4 * XK + lane]);
                    float t5 = bf2f(Xb[u5 * XK + lane]);
                    float t6 = bf2f(Xb[u6 * XK + lane]);
                    float t7 = bf2f(Xb[u7 * XK + lane]);
                    a0 += (t0 + t1) + (t2 + t3);
                    a1 += (t4 + t5) + (t6 + t7);
                }
                for (; i + 2 <= e; i += 2) {
                    a0 += bf2f(Xb[colu[i] * XK + lane]);
                    a1 += bf2f(Xb[colu[i + 1] * XK + lane]);
                }
                if (i < e) a0 += bf2f(Xb[colu[i] * XK + lane]);
            }
            float inv = 0.f;
            if (e > s) { inv = 1.0f / (float)(e - s); mul = 2.f; }
            float self = (lane < XK) ? bf2f(Xb[(size_t)v * XK + lane]) : 0.f;
            val = self + inv * (a0 + a1);
        }
        tl1[r * K1S + lane] = (lane < XK) ? f2bf(val) : (unsigned short)0;
        if (lane == 0) bpm[r] = mul;
    }
    if (tid < 64) gl[tid] = (m0 + tid < N_NODES) ? gid[m0 + tid] : -1;
    __syncthreads();

    // ---- phase 2: MFMA stage 1 (A = tl1 64x64, B = WprojPack) ----
    int n0 = w * 32;
    f32x4 acc[4][2];
#pragma unroll
    for (int mt = 0; mt < 4; mt++) {
        acc[mt][0] = (f32x4){0.f, 0.f, 0.f, 0.f};
        acc[mt][1] = (f32x4){0.f, 0.f, 0.f, 0.f};
    }
#pragma unroll
    for (int ks = 0; ks < 2; ks++) {
        int kg = ks * 4 + quad;
        short8v bfr0 = *(const short8v*)(WprojPack + (size_t)(kg * 256 + n0 + l16) * 8);
        short8v bfr1 = *(const short8v*)(WprojPack + (size_t)(kg * 256 + n0 + 16 + l16) * 8);
#pragma unroll
        for (int mt = 0; mt < 4; mt++) {
            short8v afr = *(const short8v*)(tl1 + (mt * 16 + l16) * K1S + ks * 32 + quad * 8);
            acc[mt][0] = __builtin_amdgcn_mfma_f32_16x16x32_bf16(afr, bfr0, acc[mt][0], 0, 0, 0);
            acc[mt][1] = __builtin_amdgcn_mfma_f32_16x16x32_bf16(afr, bfr1, acc[mt][1], 0, 0, 0);
        }
    }
    __syncthreads();   // all tl1 reads complete before tl writes (overlay!)
#pragma unroll
    for (int nt = 0; nt < 2; nt++) {
        int colg = n0 + nt * 16 + l16;
        float bb = bp[colg];
#pragma unroll
        for (int mt = 0; mt < 4; mt++)
#pragma unroll
            for (int r = 0; r < 4; r++) {
                int row = mt * 16 + quad * 4 + r;
                tl[row * TLS + colg] = f2bf(acc[mt][nt][r] + bb * bpm[row]);
            }
    }
    __syncthreads();

    // ---- phase 3: MFMA stage 2 (A = tl 64x256, B = WlPack) ----
#pragma unroll
    for (int mt = 0; mt < 4; mt++) {
        acc[mt][0] = (f32x4){0.f, 0.f, 0.f, 0.f};
        acc[mt][1] = (f32x4){0.f, 0.f, 0.f, 0.f};
    }
#pragma unroll
    for (int ks = 0; ks < 8; ks++) {
        int kg = ks * 4 + quad;
        short8v bfr0 = *(const short8v*)(WlPack + (size_t)(kg * 256 + n0 + l16) * 8);
        short8v bfr1 = *(const short8v*)(WlPack + (size_t)(kg * 256 + n0 + 16 + l16) * 8);
#pragma unroll
        for (int mt = 0; mt < 4; mt++) {
            short8v afr = *(const short8v*)(tl + (mt * 16 + l16) * TLS + ks * 32 + quad * 8);
            acc[mt][0] = __builtin_amdgcn_mfma_f32_16x16x32_bf16(afr, bfr0, acc[mt][0], 0, 0, 0);
            acc[mt][1] = __builtin_amdgcn_mfma_f32_16x16x32_bf16(afr, bfr1, acc[mt][1], 0, 0, 0);
        }
    }
    __syncthreads();

    // ---- phase 4: epilogue ----
#pragma unroll
    for (int nt = 0; nt < 2; nt++) {
        int colg = n0 + nt * 16 + l16;
        float bb = bl[colg];
#pragma unroll
        for (int mt = 0; mt < 4; mt++)
#pragma unroll
            for (int r = 0; r < 4; r++)
                tl[(mt * 16 + quad * 4 + r) * TLS + colg] = f2bf(acc[mt][nt][r] + bb);
    }
    __syncthreads();

    // ---- phase 5a: coalesced stores (bf16 + fp8 mirror) ----
    for (int i = tid; i < 64 * 64; i += 512) {
        int r = i >> 6, c4 = i & 63;
        int v = m0 + r;
        if (v < N_NODES) {
            ushort4 q = *(ushort4*)(tl + r * TLS + c4 * 4);
            ((ushort4*)hout)[(size_t)v * 64 + c4] = q;
            ((unsigned int*)hout8)[(size_t)v * 64 + c4] =
                pk4fp8(bf2f(q.x), bf2f(q.y), bf2f(q.z), bf2f(q.w));
        }
    }
    // ---- phase 5b: fused readout ----
    {
        int c = tid & 255;
        int r0 = (tid >> 8) * 32;
        float a2 = 0.f;
        int curg = gl[r0];
        for (int r = r0; r < r0 + 32; r++) {
            int g = gl[r];
            if (g < 0) break;
            if (g != curg) {
                atomicAdd(&GsumL[curg * HIDDEN + c], a2);
                a2 = 0.f;
                curg = g;
            }
            a2 += bf2f(tl[r * TLS + c]);
        }
        if (curg >= 0) atomicAdd(&GsumL[curg * HIDDEN + c], a2);
    }
}

// ====== fused layer (2,3): fp8 gather (8 in flight) -> MFMA -> store ========
__global__ __launch_bounds__(512, 8) void k_layer(const unsigned short* __restrict__ h,
                                                  const unsigned char* __restrict__ h8,
                                                  const int* __restrict__ row_ptr,
                                                  const unsigned short* __restrict__ colu,
                                                  const unsigned short* __restrict__ Wpack,
                                                  const float* __restrict__ bias,
                                                  const int* __restrict__ gid,
                                                  unsigned short* __restrict__ hout,
                                                  unsigned char* __restrict__ hout8,
                                                  int write8,
                                                  float* __restrict__ GsumL) {
    __shared__ unsigned short tl[64 * TLS];   // 33792 B
    __shared__ int gl[64];
    int tid = threadIdx.x;
    int w = tid >> 6, lane = tid & 63, quad = lane >> 4, l16 = lane & 15;
    int m0 = blockIdx.x * 64;

    // ---- phase 1: fp8 gather + mean into LDS tile; 8 loads in flight ----
    const unsigned int* h8v = (const unsigned int*)h8;   // 4 fp8 per lane (4 B)
    const ushort4* hv = (const ushort4*)h;
    for (int rr = 0; rr < 8; rr++) {
        int r = w * 8 + rr;
        int v = m0 + r;
        float a0 = 0.f, a1 = 0.f, a2 = 0.f, a3 = 0.f;
        if (v < N_NODES) {
            int s = row_ptr[v], e = row_ptr[v + 1];
            int i = s;
            for (; i + 8 <= e; i += 8) {
                int u0 = colu[i],     u1 = colu[i + 1];
                int u2 = colu[i + 2], u3 = colu[i + 3];
                int u4 = colu[i + 4], u5 = colu[i + 5];
                int u6 = colu[i + 6], u7 = colu[i + 7];
                unsigned int p0 = h8v[(size_t)u0 * 64 + lane];
                unsigned int p1 = h8v[(size_t)u1 * 64 + lane];
                unsigned int p2 = h8v[(size_t)u2 * 64 + lane];
                unsigned int p3 = h8v[(size_t)u3 * 64 + lane];
                unsigned int p4 = h8v[(size_t)u4 * 64 + lane];
                unsigned int p5 = h8v[(size_t)u5 * 64 + lane];
                unsigned int p6 = h8v[(size_t)u6 * 64 + lane];
                unsigned int p7 = h8v[(size_t)u7 * 64 + lane];
                a0 += (fp8tof<0>(p0) + fp8tof<0>(p1)) + (fp8tof<0>(p2) + fp8tof<0>(p3))
                    + (fp8tof<0>(p4) + fp8tof<0>(p5)) + (fp8tof<0>(p6) + fp8tof<0>(p7));
                a1 += (fp8tof<1>(p0) + fp8tof<1>(p1)) + (fp8tof<1>(p2) + fp8tof<1>(p3))
                    + (fp8tof<1>(p4) + fp8tof<1>(p5)) + (fp8tof<1>(p6) + fp8tof<1>(p7));
                a2 += (fp8tof<2>(p0) + fp8tof<2>(p1)) + (fp8tof<2>(p2) + fp8tof<2>(p3))
                    + (fp8tof<2>(p4) + fp8tof<2>(p5)) + (fp8tof<2>(p6) + fp8tof<2>(p7));
                a3 += (fp8tof<3>(p0) + fp8tof<3>(p1)) + (fp8tof<3>(p2) + fp8tof<3>(p3))
                    + (fp8tof<3>(p4) + fp8tof<3>(p5)) + (fp8tof<3>(p6) + fp8tof<3>(p7));
            }
            for (; i + 4 <= e; i += 4) {
                int u0 = colu[i], u1 = colu[i + 1], u2 = colu[i + 2], u3 = colu[i + 3];
                unsigned int p0 = h8v[(size_t)u0 * 64 + lane];
                unsigned int p1 = h8v[(size_t)u1 * 64 + lane];
                unsigned int p2 = h8v[(size_t)u2 * 64 + lane];
                unsigned int p3 = h8v[(size_t)u3 * 64 + lane];
                a0 += (fp8tof<0>(p0) + fp8tof<0>(p1)) + (fp8tof<0>(p2) + fp8tof<0>(p3));
                a1 += (fp8tof<1>(p0) + fp8tof<1>(p1)) + (fp8tof<1>(p2) + fp8tof<1>(p3));
                a2 += (fp8tof<2>(p0) + fp8tof<2>(p1)) + (fp8tof<2>(p2) + fp8tof<2>(p3));
                a3 += (fp8tof<3>(p0) + fp8tof<3>(p1)) + (fp8tof<3>(p2) + fp8tof<3>(p3));
            }
            for (; i < e; i++) {
                unsigned int p = h8v[(size_t)colu[i] * 64 + lane];
                a0 += fp8tof<0>(p); a1 += fp8tof<1>(p);
                a2 += fp8tof<2>(p); a3 += fp8tof<3>(p);
            }
            float inv = (e > s) ? 1.0f / (float)(e - s) : 0.0f;
            ushort4 hs = hv[(size_t)v * 64 + lane];   // self-term bf16
            a0 = bf2f(hs.x) + inv * a0;
            a1 = bf2f(hs.y) + inv * a1;
            a2 = bf2f(hs.z) + inv * a2;
            a3 = bf2f(hs.w) + inv * a3;
        }
        ushort4 o;
        o.x = f2bf(a0); o.y = f2bf(a1); o.z = f2bf(a2); o.w = f2bf(a3);
        *(ushort4*)(tl + r * TLS + lane * 4) = o;
    }
    if (tid < 64) gl[tid] = (m0 + tid < N_NODES) ? gid[m0 + tid] : -1;
    __syncthreads();

    // ---- phase 2: MFMA ----
    int n0 = w * 32;
    f32x4 acc[4][2];
#pragma unroll
    for (int mt = 0; mt < 4; mt++) {
        acc[mt][0] = (f32x4){0.f, 0.f, 0.f, 0.f};
        acc[mt][1] = (f32x4){0.f, 0.f, 0.f, 0.f};
    }
#pragma unroll
    for (int ks = 0; ks < 8; ks++) {
        int kg = ks * 4 + quad;
        short8v bfr0 = *(const short8v*)(Wpack + (size_t)(kg * 256 + n0 + l16) * 8);
        short8v bfr1 = *(const short8v*)(Wpack + (size_t)(kg * 256 + n0 + 16 + l16) * 8);
#pragma unroll
        for (int mt = 0; mt < 4; mt++) {
            short8v afr = *(const short8v*)(tl + (mt * 16 + l16) * TLS + ks * 32 + quad * 8);
            acc[mt][0] = __builtin_amdgcn_mfma_f32_16x16x32_bf16(afr, bfr0, acc[mt][0], 0, 0, 0);
            acc[mt][1] = __builtin_amdgcn_mfma_f32_16x16x32_bf16(afr, bfr1, acc[mt][1], 0, 0, 0);
        }
    }
    __syncthreads();

    // ---- phase 3: epilogue ----
#pragma unroll
    for (int nt = 0; nt < 2; nt++) {
        int colg = n0 + nt * 16 + l16;
        float bb = bias[colg];
#pragma unroll
        for (int mt = 0; mt < 4; mt++)
#pragma unroll
            for (int r = 0; r < 4; r++)
                tl[(mt * 16 + quad * 4 + r) * TLS + colg] = f2bf(acc[mt][nt][r] + bb);
    }
    __syncthreads();

    // ---- phase 4a: coalesced stores (bf16 + optional fp8 mirror) ----
    for (int i = tid; i < 64 * 64; i += 512) {
        int r = i >> 6, c4 = i & 63;
        int v = m0 + r;
        if (v < N_NODES) {
            ushort4 q = *(ushort4*)(tl + r * TLS + c4 * 4);
            ((ushort4*)hout)[(size_t)v * 64 + c4] = q;
            if (write8)
                ((unsigned int*)hout8)[(size_t)v * 64 + c4] =
                    pk4fp8(bf2f(q.x), bf2f(q.y), bf2f(q.z), bf2f(q.w));
        }
    }
    // ---- phase 4b: fused readout ----
    {
        int c = tid & 255;
        int r0 = (tid >> 8) * 32;
        float a2 = 0.f;
        int curg = gl[r0];
        for (int r = r0; r < r0 + 32; r++) {
            int g = gl[r];
            if (g < 0) break;
            if (g != curg) {
                atomicAdd(&GsumL[curg * HIDDEN + c], a2);
                a2 = 0.f;
                curg = g;
            }
            a2 += bf2f(tl[r * TLS + c]);
        }
        if (curg >= 0) atomicAdd(&GsumL[curg * HIDDEN + c], a2);
    }
}

// ================= out[g] = (concat gmean) @ W_out + b_out ==================
__global__ __launch_bounds__(256) void k_out(const float* __restrict__ Gsum,
                                             const int* __restrict__ gcnt,
                                             const float* __restrict__ Wout,
                                             const float* __restrict__ bout,
                                             float* __restrict__ out) {
    int g = blockIdx.x;
    int c = threadIdx.x;
    __shared__ float gm[HIDDEN * CONV_NUMS];
    float invc = 1.0f / fmaxf((float)gcnt[g], 1.0f);
    for (int i = c; i < HIDDEN * CONV_NUMS; i += 256) {
        int l = i >> 8;
        int k = i & 255;
        gm[i] = Gsum[(size_t)l * N_GRAPHS * HIDDEN + g * HIDDEN + k] * invc;
    }
    __syncthreads();
    float acc = bout[c];
    const float4* gm4 = (const float4*)gm;
    for (int k0 = 0; k0 < HIDDEN * CONV_NUMS; k0 += 4) {
        float4 gv = gm4[k0 >> 2];
        acc += gv.x * Wout[(k0 + 0) * HIDDEN + c];
        acc += gv.y * Wout[(k0 + 1) * HIDDEN + c];
        acc += gv.z * Wout[(k0 + 2) * HIDDEN + c];
        acc += gv.w * Wout[(k0 + 3) * HIDDEN + c];
    }
    out[g * HIDDEN + c] = acc;
}

extern "C" void kernel_launch(void* const* d_in, const int* in_sizes, int n_in,
                              void* d_out, int out_size, void* d_ws, size_t ws_size,
                              hipStream_t stream) {
    const float* X    = (const float*)d_in[0];
    const int*   src  = (const int*)d_in[1];
    const int*   dst  = (const int*)d_in[2];
    const int*   gid  = (const int*)d_in[3];
    const float* Wp   = (const float*)d_in[4];
    const float* bp   = (const float*)d_in[5];
    const float* Wl   = (const float*)d_in[6];
    const float* bl   = (const float*)d_in[7];
    const float* Wout = (const float*)d_in[8];
    const float* bout = (const float*)d_in[9];
    float* out = (float*)d_out;

    char* ws = (char*)d_ws;
    size_t off = 0;
    auto alloc = [&](size_t bytes) {
        char* p = ws + off;
        off += (bytes + 255) & ~size_t(255);
        return p;
    };
    unsigned short* h         = (unsigned short*)alloc(sizeof(short) * N_NODES * HIDDEN);
    unsigned short* t         = (unsigned short*)alloc(sizeof(short) * N_NODES * HIDDEN);
    unsigned char*  h8a       = (unsigned char*)alloc((size_t)N_NODES * HIDDEN);
    unsigned char*  h8b       = (unsigned char*)alloc((size_t)N_NODES * HIDDEN);
    unsigned short* WlPack    = (unsigned short*)alloc(sizeof(short) * HIDDEN * HIDDEN);
    unsigned short* WprojPack = (unsigned short*)alloc(sizeof(short) * 8 * 256 * 8);
    unsigned short* Xb        = (unsigned short*)alloc(sizeof(short) * N_NODES * XK);
    int*   pairs   = (int*)alloc(sizeof(int) * N_EDGES);
    unsigned short* colu = (unsigned short*)alloc(sizeof(short) * N_EDGES);
    int*   row_ptr = (int*)alloc(sizeof(int) * (N_NODES + 1));
    int*   bucket_base   = (int*)alloc(sizeof(int) * (NBK + 1));
    int*   bucket_cursor = (int*)alloc(sizeof(int) * NBK);
    // contiguous zero region: bucket_cnt | gcnt | Gsum  -> one memset
    char*  zero0 = ws + off;
    int*   bucket_cnt = (int*)alloc(sizeof(int) * NBK);
    int*   gcnt       = (int*)alloc(sizeof(int) * N_GRAPHS);
    float* Gsum       = (float*)alloc(sizeof(float) * CONV_NUMS * N_GRAPHS * HIDDEN);
    size_t zero_bytes = (size_t)((char*)(Gsum + CONV_NUMS * N_GRAPHS * HIDDEN) - zero0);

    hipMemsetAsync(zero0, 0, zero_bytes, stream);

    k_passA<<<512, 256, 0, stream>>>(dst, gid, bucket_cnt, gcnt);
    k_bscan<<<1, 256, 0, stream>>>(bucket_cnt, bucket_base, bucket_cursor, row_ptr);
    k_passB<<<(N_EDGES + BCH - 1) / BCH, 256, 0, stream>>>(src, dst, bucket_cursor, pairs);
    {
        const int TOT = N_NODES * XK;
        int ncast = (TOT + 2047) / 2048;
        k_prep<<<40 + ncast, 256, 0, stream>>>(Wl, Wp, X, WlPack, WprojPack, Xb);
    }
    k_passC<<<NBK, 256, 0, stream>>>(pairs, bucket_base, row_ptr, colu);

    // layer 1 (fused proj + conv1 + readout); writes bf16 h + fp8 mirror h8a
    k_layer1<<<(N_NODES + 63) / 64, 512, 0, stream>>>(
        Xb, row_ptr, colu, WprojPack, bp, WlPack, bl, gid, h, h8a, Gsum);

    // layer 2: gather fp8(h8a), self bf16 h -> t + h8b
    k_layer<<<(N_NODES + 63) / 64, 512, 0, stream>>>(
        h, h8a, row_ptr, colu, WlPack, bl, gid, t, h8b, 1,
        Gsum + (size_t)1 * N_GRAPHS * HIDDEN);

    // layer 3: gather fp8(h8b), self bf16 t -> h (no fp8 mirror needed)
    k_layer<<<(N_NODES + 63) / 64, 512, 0, stream>>>(
        t, h8b, row_ptr, colu, WlPack, bl, gid, h, h8a, 0,
        Gsum + (size_t)2 * N_GRAPHS * HIDDEN);

    k_out<<<N_GRAPHS, 256, 0, stream>>>(Gsum, gcnt, Wout, bout, out);
}